// Round 11
// baseline (872.989 us; speedup 1.0000x reference)
//
#include <hip/hip_runtime.h>
#include <hip/hip_bf16.h>
#include <math.h>

#define N_ATOMS 16384
#define N_EDGES 262144
#define DIM 128
#define NF 128
#define NG 50
#define NL 4
#define NMOLS 32
#define EW 8   // waves per block
#define EB 4   // rows per wave batch (fp32 node gemm)

typedef short bf16x8 __attribute__((ext_vector_type(8)));
typedef float f32x4 __attribute__((ext_vector_type(4)));

__device__ __forceinline__ float ssp_f(float x) {
    // softplus(x) - log(2) = max(x,0) + log(1 + exp(-|x|)) - log(2)
    float e = __expf(-fabsf(x));
    return fmaxf(x, 0.0f) + __logf(1.0f + e) - 0.6931471805599453f;
}

__device__ __forceinline__ short f2bf(float x) {
    __hip_bfloat16 b = __float2bfloat16(x);  // RNE
    return *reinterpret_cast<short*>(&b);
}

__device__ __forceinline__ float bf2f(unsigned short u) {
    unsigned int v = ((unsigned int)u) << 16;
    return __builtin_bit_cast(float, v);
}

// h[n][d] = z[n]*emb_W[d] + emb_b[d]
__global__ void k_embed(const float* __restrict__ z, const float* __restrict__ Wv,
                        const float* __restrict__ bv, float* __restrict__ h) {
    int idx = blockIdx.x * blockDim.x + threadIdx.x;
    int n = idx >> 7, d = idx & 127;
    h[idx] = z[n] * Wv[d] + bv[d];
}

// dist[e], C[e]
__global__ void k_geom(const float* __restrict__ pos, const int* __restrict__ src,
                       const int* __restrict__ dst, float* __restrict__ dist,
                       float* __restrict__ Cenv) {
    int e = blockIdx.x * blockDim.x + threadIdx.x;
    if (e >= N_EDGES) return;
    int s = src[e], t = dst[e];
    float dx = pos[3*s]   - pos[3*t];
    float dy = pos[3*s+1] - pos[3*t+1];
    float dz = pos[3*s+2] - pos[3*t+2];
    float d = sqrtf(dx*dx + dy*dy + dz*dz + 1e-12f);
    dist[e] = d;
    Cenv[e] = 0.5f * (cosf(d * (float)(M_PI / 5.0)) + 1.0f);
}

// ---- CSR build: sort edges by dst via counting sort ----
__global__ void k_deg(const int* __restrict__ dst, int* __restrict__ deg) {
    int e = blockIdx.x * blockDim.x + threadIdx.x;
    if (e < N_EDGES) atomicAdd(&deg[dst[e]], 1);
}

__global__ __launch_bounds__(1024)
void k_scan(const int* __restrict__ deg, int* __restrict__ cur) {
    __shared__ int tot[1024];
    int t = threadIdx.x;
    int v[16];
    int s = 0;
    #pragma unroll
    for (int j = 0; j < 16; ++j) { int x = deg[t * 16 + j]; v[j] = s; s += x; }
    tot[t] = s;
    __syncthreads();
    for (int off = 1; off < 1024; off <<= 1) {
        int add = (t >= off) ? tot[t - off] : 0;
        __syncthreads();
        tot[t] += add;
        __syncthreads();
    }
    int base = (t == 0) ? 0 : tot[t - 1];
    #pragma unroll
    for (int j = 0; j < 16; ++j) cur[t * 16 + j] = base + v[j];
}

__global__ void k_fill(const int* __restrict__ dst, int* __restrict__ cur,
                       int* __restrict__ edge_of) {
    int e = blockIdx.x * blockDim.x + threadIdx.x;
    if (e < N_EDGES) {
        int p = atomicAdd(&cur[dst[e]], 1);
        edge_of[p] = e;
    }
}

__global__ void k_perm(const int* __restrict__ edge_of, const float* __restrict__ dist,
                       const float* __restrict__ Cenv, const int* __restrict__ src,
                       const int* __restrict__ dst, float* __restrict__ distS,
                       float* __restrict__ CenvS, int* __restrict__ srcS,
                       int* __restrict__ dstS) {
    int p = blockIdx.x * blockDim.x + threadIdx.x;
    if (p >= N_EDGES) return;
    int e = edge_of[p];
    distS[p] = dist[e];
    CenvS[p] = Cenv[e];
    srcS[p]  = src[e];
    dstS[p]  = dst[e];
}

// Precompute rbf in MFMA A-fragment layout, SLOT order (layer-invariant, used 4x).
__global__ __launch_bounds__(512)
void k_rbf(const float* __restrict__ distS, short* __restrict__ rbfF) {
    int lane = threadIdx.x & 63;
    int w    = threadIdx.x >> 6;
    int t    = blockIdx.x * 8 + w;            // tile = 16 slots
    int q = lane >> 4, m = lane & 15;
    float d = distS[t * 16 + m];
    #pragma unroll
    for (int kc = 0; kc < 2; ++kc) {
        bf16x8 v;
        #pragma unroll
        for (int j = 0; j < 8; ++j) {
            float mu = (float)(kc * 32 + q * 8 + j) * (5.0f / 49.0f);
            float tt = d - mu;
            v[j] = f2bf(__expf(-4.0f * tt * tt));   // k>=50 rows hit zero W1R
        }
        *(bf16x8*)&rbfF[(size_t)((t * 2 + kc) * 64 + lane) * 8] = v;
    }
}

// MFMA edge pipeline over dst-sorted slots. Block = 8 waves; round = 64 slots.
// ONE barrier/round: H1 double-buffered; msgt columns are wave-private (wave w
// writes/reads only cols [w*16,w*16+16)); per-wave ballot for run structure;
// segment-sum done by MFMA with a 0/1 indicator matrix S (fallback serial loop
// if nruns > 16, statistically negligible).
__global__ __launch_bounds__(512, 4)
void k_edge_csr(const short* __restrict__ rbfF, const float* __restrict__ CenvS,
                const int* __restrict__ srcS, const int* __restrict__ dstS,
                const float* __restrict__ W1, const float* __restrict__ b1,
                const float* __restrict__ W2, const float* __restrict__ b2,
                const unsigned short* __restrict__ xjb, float* __restrict__ agg)
{
    __shared__ short H1s[2][64 * 128];           // 32 KB double buffer
    __shared__ unsigned short msgt[64][136];     // 17 KB bf16 message tile (wave-private cols)
    __shared__ int dsthW[EW][16];                // per-wave run-head dst values
    const int tid  = threadIdx.x;
    const int lane = tid & 63;
    const int w    = tid >> 6;     // wave id = filter block
    const int q    = lane >> 4;
    const int m    = lane & 15;

    bf16x8 W1R[2], W2R[4];
    #pragma unroll
    for (int kc = 0; kc < 2; ++kc) {
        bf16x8 f;
        #pragma unroll
        for (int j = 0; j < 8; ++j) {
            int k = kc * 32 + q * 8 + j;
            float v = (k < NG) ? W1[k * NF + w * 16 + m] : 0.0f;  // pad G 50->64
            f[j] = f2bf(v);
        }
        W1R[kc] = f;
    }
    #pragma unroll
    for (int kc = 0; kc < 4; ++kc) {
        bf16x8 f;
        #pragma unroll
        for (int j = 0; j < 8; ++j) {
            int k = kc * 32 + q * 8 + j;
            f[j] = f2bf(W2[k * NF + w * 16 + m]);
        }
        W2R[kc] = f;
    }
    const float b1v = b1[w * 16 + m];
    const float b2v = b2[w * 16 + m];

    const int nrounds = N_EDGES / 64;
    int rb = 0;
    for (int r = blockIdx.x; r < nrounds; r += gridDim.x, ++rb) {
        const int p0 = r * 64;
        short* H = H1s[rb & 1];

        // ---- matvec1: A from precomputed rbfF + ssp + swizzled H1 store ----
        #pragma unroll
        for (int a = 0; a < 4; ++a) {
            int tile = r * 4 + a;
            f32x4 acc = {b1v, b1v, b1v, b1v};
            #pragma unroll
            for (int kc = 0; kc < 2; ++kc) {
                bf16x8 A = *(const bf16x8*)&rbfF[(size_t)((tile * 2 + kc) * 64 + lane) * 8];
                acc = __builtin_amdgcn_mfma_f32_16x16x32_bf16(A, W1R[kc], acc, 0, 0, 0);
            }
            #pragma unroll
            for (int i = 0; i < 4; ++i) {
                int e = a * 16 + q * 4 + i;
                int f = w * 16 + m;
                int byte = (e * 256 + f * 2) ^ ((e & 7) << 4);
                *(short*)((char*)H + byte) = f2bf(ssp_f(acc[i]));
            }
        }

        // ---- issue xj gathers before the barrier; they fly during matvec2 ----
        unsigned short xu[4][4];
        #pragma unroll
        for (int a = 0; a < 4; ++a) {
            int4 s4 = *(const int4*)&srcS[p0 + a * 16 + q * 4];
            #pragma unroll
            for (int i = 0; i < 4; ++i)
                xu[a][i] = xjb[(size_t)((const int*)&s4)[i] * NF + w * 16 + m];
        }
        // per-wave run structure (redundant across waves; no cross-wave sharing)
        int dstv = dstS[p0 + lane];
        int prev = __shfl_up(dstv, 1);
        bool head = (lane == 0) || (dstv != prev);
        unsigned long long mk = __ballot(head);
        int nruns = __popcll(mk);
        {
            int rid = __popcll(mk & ((1ull << lane) - 1ull));
            if (head && rid < 16) dsthW[w][rid] = dstv;
        }

        __syncthreads();   // single barrier: H1 ready; prev round's H1 reads done

        // ---- matvec2: Wf = H1 @ W2 + b2 ----
        f32x4 acc2[4];
        #pragma unroll
        for (int a = 0; a < 4; ++a) {
            f32x4 acc = {b2v, b2v, b2v, b2v};
            #pragma unroll
            for (int kc = 0; kc < 4; ++kc) {
                int e = a * 16 + m;
                int byte = (e * 256 + (kc * 32 + q * 8) * 2) ^ ((e & 7) << 4);
                bf16x8 A = *(const bf16x8*)((const char*)H + byte);  // ds_read_b128
                acc = __builtin_amdgcn_mfma_f32_16x16x32_bf16(A, W2R[kc], acc, 0, 0, 0);
            }
            acc2[a] = acc;
        }

        // ---- messages -> wave-private msgt cols (bf16): v = Wf * C * xv ----
        #pragma unroll
        for (int a = 0; a < 4; ++a) {
            float4 cc4 = *(const float4*)&CenvS[p0 + a * 16 + q * 4];
            #pragma unroll
            for (int i = 0; i < 4; ++i) {
                float v = acc2[a][i] * ((const float*)&cc4)[i];
                msgt[a * 16 + q * 4 + i][w * 16 + m] =
                    (unsigned short)f2bf(v * bf2f(xu[a][i]));
            }
        }

        // ---- segment reduce (wave-local; no barrier needed) ----
        if (nruns <= 16) {
            // B-frag: M[k=slot][col=m] from this wave's msgt columns
            bf16x8 Mf[2];
            #pragma unroll
            for (int kc = 0; kc < 2; ++kc) {
                bf16x8 t;
                #pragma unroll
                for (int j = 0; j < 8; ++j)
                    t[j] = (short)msgt[kc * 32 + q * 8 + j][w * 16 + m];
                Mf[kc] = t;
            }
            // A-frag: S[row=run m][k=slot] indicator, D = S @ M
            f32x4 D = {0.0f, 0.0f, 0.0f, 0.0f};
            #pragma unroll
            for (int kc = 0; kc < 2; ++kc) {
                bf16x8 S;
                #pragma unroll
                for (int j = 0; j < 8; ++j) {
                    int s = kc * 32 + q * 8 + j;
                    unsigned long long pm = (2ull << s) - 1ull;  // s=63 wraps to ~0
                    int rid = __popcll(mk & pm) - 1;
                    S[j] = (rid == m) ? (short)0x3F80 : (short)0;
                }
                D = __builtin_amdgcn_mfma_f32_16x16x32_bf16(S, Mf[kc], D, 0, 0, 0);
            }
            // C/D: lane (q,m) holds D[run q*4+i][filter w*16+m]
            #pragma unroll
            for (int i = 0; i < 4; ++i) {
                int rr = q * 4 + i;
                if (rr < nruns) {
                    float* addr = &agg[(size_t)dsthW[w][rr] * NF + w * 16 + m];
                    if (rr == 0 || rr == nruns - 1) atomicAdd(addr, D[i]);  // may straddle rounds
                    else *addr = D[i];                                       // run exclusive here
                }
            }
        } else {
            // rare fallback: serial per-run reduce (runs round-robin over quarters)
            unsigned long long mm = mk;
            int k = 0;
            while (mm) {
                int start = __ffsll(mm) - 1;
                mm &= mm - 1;
                int end = mm ? (__ffsll(mm) - 1) : 64;
                int dstart = __shfl(dstv, start);   // uniform-exec shfl
                if ((k & 3) == q) {
                    float s = 0.0f;
                    for (int p = start; p < end; ++p) s += bf2f(msgt[p][w * 16 + m]);
                    float* addr = &agg[(size_t)dstart * NF + w * 16 + m];
                    if (start == 0 || end == 64) atomicAdd(addr, s);
                    else *addr = s;
                }
                ++k;
            }
        }
    }
}

// MFMA node GEMM: out[N,128] = post(in[N,128] @ W[128,128] + bias) (+ resid)
// OUTBF: write bf16 (ushort) output instead of f32.
template<int ACT, int RESID, int OUTBF>
__global__ __launch_bounds__(512, 2)
void k_node_mfma(const float* __restrict__ in, const float* __restrict__ W,
                 const float* __restrict__ bias, const float* __restrict__ resid,
                 void* __restrict__ outv)
{
    __shared__ short T[64 * 128];   // 16 KB swizzled bf16 tile
    const int tid  = threadIdx.x;
    const int lane = tid & 63;
    const int w    = tid >> 6;
    const int q    = lane >> 4;
    const int m    = lane & 15;

    bf16x8 WR[4];
    #pragma unroll
    for (int kc = 0; kc < 4; ++kc) {
        bf16x8 f;
        #pragma unroll
        for (int j = 0; j < 8; ++j)
            f[j] = f2bf(W[(kc * 32 + q * 8 + j) * DIM + w * 16 + m]);
        WR[kc] = f;
    }
    const float bv = bias ? bias[w * 16 + m] : 0.0f;

    const int r0 = blockIdx.x * 64;

    {
        int row = tid >> 3;
        int k0  = (tid & 7) * 16;
        const float* src = in + (size_t)(r0 + row) * DIM + k0;
        float4 v0 = *(const float4*)(src);
        float4 v1 = *(const float4*)(src + 4);
        float4 v2 = *(const float4*)(src + 8);
        float4 v3 = *(const float4*)(src + 12);
        bf16x8 lo, hi;
        #pragma unroll
        for (int j = 0; j < 4; ++j) {
            lo[j]     = f2bf(((const float*)&v0)[j]);
            lo[j + 4] = f2bf(((const float*)&v1)[j]);
            hi[j]     = f2bf(((const float*)&v2)[j]);
            hi[j + 4] = f2bf(((const float*)&v3)[j]);
        }
        int b0 = (row * 256 + k0 * 2)       ^ ((row & 7) << 4);
        int b1 = (row * 256 + (k0 + 8) * 2) ^ ((row & 7) << 4);
        *(bf16x8*)((char*)T + b0) = lo;
        *(bf16x8*)((char*)T + b1) = hi;
    }
    __syncthreads();

    #pragma unroll
    for (int a = 0; a < 4; ++a) {
        f32x4 acc = {bv, bv, bv, bv};
        int row = a * 16 + m;
        #pragma unroll
        for (int kc = 0; kc < 4; ++kc) {
            int byte = (row * 256 + (kc * 32 + q * 8) * 2) ^ ((row & 7) << 4);
            bf16x8 A = *(const bf16x8*)((const char*)T + byte);
            acc = __builtin_amdgcn_mfma_f32_16x16x32_bf16(A, WR[kc], acc, 0, 0, 0);
        }
        #pragma unroll
        for (int i = 0; i < 4; ++i) {
            float v = acc[i];
            if (ACT) v = ssp_f(v);
            size_t oi = (size_t)(r0 + a * 16 + q * 4 + i) * DIM + w * 16 + m;
            if (RESID) v += resid[oi];
            if (OUTBF) ((unsigned short*)outv)[oi] = (unsigned short)f2bf(v);
            else       ((float*)outv)[oi] = v;
        }
    }
}

// fp32 node GEMM kept for lin1 (COLS=64)
template<int COLS, int ACT, int RESID>
__global__ __launch_bounds__(512)
void k_node_gemm(const float* __restrict__ in, const float* __restrict__ W,
                 const float* __restrict__ bias, const float* __restrict__ resid,
                 float* __restrict__ out)
{
    __shared__ float Ws[DIM][COLS];
    __shared__ float rs[EW][EB][DIM];
    int tid = threadIdx.x;
    for (int i = tid; i < DIM * COLS; i += 512) (&Ws[0][0])[i] = W[i];
    __syncthreads();

    int lane = tid & 63;
    int w = tid >> 6;
    int gw = blockIdx.x * EW + w;
    int nw = gridDim.x * EW;
    int ngroups = N_ATOMS / EB;
    constexpr int CPL = COLS / 64;

    float bb[CPL];
    #pragma unroll
    for (int c = 0; c < CPL; ++c) bb[c] = bias ? bias[lane + 64 * c] : 0.0f;

    for (int grp = gw; grp < ngroups; grp += nw) {
        int r0 = grp * EB;
        #pragma unroll
        for (int r = 0; r < EB; ++r) {
            rs[w][r][lane]      = in[(size_t)(r0 + r) * DIM + lane];
            rs[w][r][lane + 64] = in[(size_t)(r0 + r) * DIM + lane + 64];
        }
        float acc[EB][CPL];
        #pragma unroll
        for (int r = 0; r < EB; ++r)
            #pragma unroll
            for (int c = 0; c < CPL; ++c) acc[r][c] = bb[c];
        #pragma unroll 2
        for (int kb = 0; kb < DIM / 4; ++kb) {
            float4 rv[EB];
            #pragma unroll
            for (int r = 0; r < EB; ++r)
                rv[r] = *(const float4*)&rs[w][r][4 * kb];
            #pragma unroll
            for (int j = 0; j < 4; ++j) {
                float wv[CPL];
                #pragma unroll
                for (int c = 0; c < CPL; ++c) wv[c] = Ws[4 * kb + j][lane + 64 * c];
                #pragma unroll
                for (int r = 0; r < EB; ++r) {
                    float rj = ((const float*)&rv[r])[j];
                    #pragma unroll
                    for (int c = 0; c < CPL; ++c)
                        acc[r][c] = fmaf(rj, wv[c], acc[r][c]);
                }
            }
        }
        #pragma unroll
        for (int r = 0; r < EB; ++r) {
            #pragma unroll
            for (int c = 0; c < CPL; ++c) {
                float v = acc[r][c];
                if (ACT) v = ssp_f(v);
                size_t oi = (size_t)(r0 + r) * COLS + lane + 64 * c;
                if (RESID) v += resid[oi];
                out[oi] = v;
            }
        }
    }
}

// per-atom: dot(r1[n], lin2W) + lin2b -> per-block LDS mol reduce -> 32 atomics
__global__ __launch_bounds__(256)
void k_final(const float* __restrict__ r1, const float* __restrict__ l2W,
             const float* __restrict__ l2b, const int* __restrict__ batch,
             float* __restrict__ out)
{
    __shared__ float mols[NMOLS];
    int tid = threadIdx.x;
    if (tid < NMOLS) mols[tid] = 0.0f;
    __syncthreads();

    int n = blockIdx.x * 256 + tid;
    const float4* row = (const float4*)(r1 + (size_t)n * 64);
    const float4* wv  = (const float4*)l2W;
    float s = 0.0f;
    #pragma unroll
    for (int k = 0; k < 16; ++k) {
        float4 a = row[k], b = wv[k];
        s += a.x * b.x + a.y * b.y + a.z * b.z + a.w * b.w;
    }
    s += l2b[0];
    atomicAdd(&mols[batch[n]], s);   // LDS atomic (block-local)
    __syncthreads();
    if (tid < NMOLS) atomicAdd(&out[tid], mols[tid]);
}

extern "C" void kernel_launch(void* const* d_in, const int* in_sizes, int n_in,
                              void* d_out, int out_size, void* d_ws, size_t ws_size,
                              hipStream_t stream) {
    const float* z     = (const float*)d_in[0];
    const float* pos   = (const float*)d_in[1];
    const int*   batch = (const int*)d_in[2];
    const int*   esrc  = (const int*)d_in[3];
    const int*   edst  = (const int*)d_in[4];
    const float* embW  = (const float*)d_in[5];
    const float* embB  = (const float*)d_in[6];
    const float* mlpW1 = (const float*)d_in[7];
    const float* mlpB1 = (const float*)d_in[8];
    const float* mlpW2 = (const float*)d_in[9];
    const float* mlpB2 = (const float*)d_in[10];
    const float* cf1W  = (const float*)d_in[11];
    const float* cf2W  = (const float*)d_in[12];
    const float* cf2B  = (const float*)d_in[13];
    const float* intW  = (const float*)d_in[14];
    const float* intB  = (const float*)d_in[15];
    const float* l1W   = (const float*)d_in[16];
    const float* l1B   = (const float*)d_in[17];
    const float* l2W   = (const float*)d_in[18];
    const float* l2B   = (const float*)d_in[19];
    float* out = (float*)d_out;

    char* ws = (char*)d_ws;
    float* h     = (float*)(ws);                        // 8 MB
    float* dist  = (float*)(ws + (size_t)( 8 << 20));   // 1 MB
    float* Cv    = (float*)(ws + (size_t)( 9 << 20));   // 1 MB
    unsigned short* xj = (unsigned short*)(ws + (size_t)(10 << 20)); // 4 MB bf16
    float* tbuf  = (float*)(ws + (size_t)(10 << 20));   // 8 MB (aliases xj; liveness-disjoint)
    float* agg   = (float*)(ws + (size_t)(18 << 20));   // 8 MB (reused as r1)
    short* rbfF  = (short*)(ws + (size_t)(26 << 20));   // 32 MB bf16 A-fragments
    int*   deg   = (int*)  (ws + (size_t)(58 << 20));   // 64 KB
    int*   cur   = (int*)  (ws + (size_t)(59 << 20));   // 64 KB
    int*   edge_of = (int*)(ws + (size_t)(60 << 20));   // 1 MB
    float* distS = (float*)(ws + (size_t)(61 << 20));   // 1 MB
    float* CenvS = (float*)(ws + (size_t)(62 << 20));   // 1 MB
    int*   srcS  = (int*)  (ws + (size_t)(63 << 20));   // 1 MB
    int*   dstS  = (int*)  (ws + (size_t)(64 << 20));   // 1 MB
    float* r1    = agg;

    k_embed<<<dim3(N_ATOMS * DIM / 512), dim3(512), 0, stream>>>(z, embW, embB, h);
    k_geom<<<dim3(N_EDGES / 256), dim3(256), 0, stream>>>(pos, esrc, edst, dist, Cv);

    // CSR build (dst-sorted slot permutation)
    hipMemsetAsync(deg, 0, N_ATOMS * sizeof(int), stream);
    k_deg<<<dim3(N_EDGES / 512), dim3(512), 0, stream>>>(edst, deg);
    k_scan<<<dim3(1), dim3(1024), 0, stream>>>(deg, cur);
    k_fill<<<dim3(N_EDGES / 512), dim3(512), 0, stream>>>(edst, cur, edge_of);
    k_perm<<<dim3(N_EDGES / 512), dim3(512), 0, stream>>>(edge_of, dist, Cv, esrc, edst,
                                                          distS, CenvS, srcS, dstS);
    k_rbf<<<dim3(N_EDGES / 16 / 8), dim3(512), 0, stream>>>(distS, rbfF);

    for (int l = 0; l < NL; ++l) {
        // cf1: h @ cf1W -> xj (bf16 out). tbuf (aliased) is dead here.
        k_node_mfma<0, 0, 1><<<dim3(N_ATOMS / 64), dim3(512), 0, stream>>>(
            h, cf1W + (size_t)l * DIM * NF, nullptr, nullptr, (void*)xj);
        hipMemsetAsync(agg, 0, (size_t)N_ATOMS * NF * sizeof(float), stream);
        k_edge_csr<<<dim3(768), dim3(512), 0, stream>>>(
            rbfF, CenvS, srcS, dstS,
            mlpW1 + (size_t)l * NG * NF, mlpB1 + (size_t)l * NF,
            mlpW2 + (size_t)l * NF * NF, mlpB2 + (size_t)l * NF,
            xj, agg);
        // cf2: ssp(agg @ cf2W + b) -> tbuf (xj dead now; alias safe)
        k_node_mfma<1, 0, 0><<<dim3(N_ATOMS / 64), dim3(512), 0, stream>>>(
            agg, cf2W + (size_t)l * NF * DIM, cf2B + (size_t)l * DIM, nullptr, (void*)tbuf);
        // int_lin: tbuf @ intW + b + h -> h
        k_node_mfma<0, 1, 0><<<dim3(N_ATOMS / 64), dim3(512), 0, stream>>>(
            tbuf, intW + (size_t)l * DIM * DIM, intB + (size_t)l * DIM, h, (void*)h);
    }

    k_node_gemm<64, 1, 0><<<dim3(256), dim3(512), 0, stream>>>(h, l1W, l1B, nullptr, r1);
    hipMemsetAsync(out, 0, NMOLS * sizeof(float), stream);
    k_final<<<dim3(N_ATOMS / 256), dim3(256), 0, stream>>>(r1, l2W, l2B, batch, out);
}

// Round 12
// 509.862 us; speedup vs baseline: 1.7122x; 1.7122x over previous
//
#include <hip/hip_runtime.h>
#include <hip/hip_bf16.h>
#include <math.h>

#define N_ATOMS 16384
#define N_EDGES 262144
#define DIM 128
#define NF 128
#define NG 50
#define NL 4
#define NMOLS 32
#define EW 8   // waves per block
#define EB 4   // rows per wave batch (fp32 node gemm)

typedef short bf16x8 __attribute__((ext_vector_type(8)));
typedef float f32x4 __attribute__((ext_vector_type(4)));

__device__ __forceinline__ float ssp_f(float x) {
    // softplus(x) - log(2) = max(x,0) + log(1 + exp(-|x|)) - log(2)
    float e = __expf(-fabsf(x));
    return fmaxf(x, 0.0f) + __logf(1.0f + e) - 0.6931471805599453f;
}

__device__ __forceinline__ short f2bf(float x) {
    __hip_bfloat16 b = __float2bfloat16(x);  // RNE
    return *reinterpret_cast<short*>(&b);
}

__device__ __forceinline__ float bf2f(unsigned short u) {
    unsigned int v = ((unsigned int)u) << 16;
    return __builtin_bit_cast(float, v);
}

// h[n][d] = z[n]*emb_W[d] + emb_b[d]
__global__ void k_embed(const float* __restrict__ z, const float* __restrict__ Wv,
                        const float* __restrict__ bv, float* __restrict__ h) {
    int idx = blockIdx.x * blockDim.x + threadIdx.x;
    int n = idx >> 7, d = idx & 127;
    h[idx] = z[n] * Wv[d] + bv[d];
}

// dist[e], C[e]
__global__ void k_geom(const float* __restrict__ pos, const int* __restrict__ src,
                       const int* __restrict__ dst, float* __restrict__ dist,
                       float* __restrict__ Cenv) {
    int e = blockIdx.x * blockDim.x + threadIdx.x;
    if (e >= N_EDGES) return;
    int s = src[e], t = dst[e];
    float dx = pos[3*s]   - pos[3*t];
    float dy = pos[3*s+1] - pos[3*t+1];
    float dz = pos[3*s+2] - pos[3*t+2];
    float d = sqrtf(dx*dx + dy*dy + dz*dz + 1e-12f);
    dist[e] = d;
    Cenv[e] = 0.5f * (cosf(d * (float)(M_PI / 5.0)) + 1.0f);
}

// ---- CSR build: sort edges by dst via counting sort ----
__global__ void k_deg(const int* __restrict__ dst, int* __restrict__ deg) {
    int e = blockIdx.x * blockDim.x + threadIdx.x;
    if (e < N_EDGES) atomicAdd(&deg[dst[e]], 1);
}

__global__ __launch_bounds__(1024)
void k_scan(const int* __restrict__ deg, int* __restrict__ cur) {
    __shared__ int tot[1024];
    int t = threadIdx.x;
    int v[16];
    int s = 0;
    #pragma unroll
    for (int j = 0; j < 16; ++j) { int x = deg[t * 16 + j]; v[j] = s; s += x; }
    tot[t] = s;
    __syncthreads();
    for (int off = 1; off < 1024; off <<= 1) {
        int add = (t >= off) ? tot[t - off] : 0;
        __syncthreads();
        tot[t] += add;
        __syncthreads();
    }
    int base = (t == 0) ? 0 : tot[t - 1];
    #pragma unroll
    for (int j = 0; j < 16; ++j) cur[t * 16 + j] = base + v[j];
}

__global__ void k_fill(const int* __restrict__ dst, int* __restrict__ cur,
                       int* __restrict__ edge_of) {
    int e = blockIdx.x * blockDim.x + threadIdx.x;
    if (e < N_EDGES) {
        int p = atomicAdd(&cur[dst[e]], 1);
        edge_of[p] = e;
    }
}

__global__ void k_perm(const int* __restrict__ edge_of, const float* __restrict__ dist,
                       const float* __restrict__ Cenv, const int* __restrict__ src,
                       const int* __restrict__ dst, float* __restrict__ distS,
                       float* __restrict__ CenvS, int* __restrict__ srcS,
                       int* __restrict__ dstS) {
    int p = blockIdx.x * blockDim.x + threadIdx.x;
    if (p >= N_EDGES) return;
    int e = edge_of[p];
    distS[p] = dist[e];
    CenvS[p] = Cenv[e];
    srcS[p]  = src[e];
    dstS[p]  = dst[e];
}

// Precompute rbf in MFMA A-fragment layout, SLOT order (layer-invariant, used 4x).
__global__ __launch_bounds__(512)
void k_rbf(const float* __restrict__ distS, short* __restrict__ rbfF) {
    int lane = threadIdx.x & 63;
    int w    = threadIdx.x >> 6;
    int t    = blockIdx.x * 8 + w;            // tile = 16 slots
    int q = lane >> 4, m = lane & 15;
    float d = distS[t * 16 + m];
    #pragma unroll
    for (int kc = 0; kc < 2; ++kc) {
        bf16x8 v;
        #pragma unroll
        for (int j = 0; j < 8; ++j) {
            float mu = (float)(kc * 32 + q * 8 + j) * (5.0f / 49.0f);
            float tt = d - mu;
            v[j] = f2bf(__expf(-4.0f * tt * tt));   // k>=50 rows hit zero W1R
        }
        *(bf16x8*)&rbfF[(size_t)((t * 2 + kc) * 64 + lane) * 8] = v;
    }
}

// MFMA edge pipeline over dst-sorted slots (r10 structure: 2 barriers/round,
// single H1 buffer, bf16 xj + bf16 msgt). Reduce inner loop is ILP-4 unrolled
// (4 independent LDS-latency chains instead of one dependent chain).
__global__ __launch_bounds__(512, 4)
void k_edge_csr(const short* __restrict__ rbfF, const float* __restrict__ CenvS,
                const int* __restrict__ srcS, const int* __restrict__ dstS,
                const float* __restrict__ W1, const float* __restrict__ b1,
                const float* __restrict__ W2, const float* __restrict__ b2,
                const unsigned short* __restrict__ xjb, float* __restrict__ agg)
{
    __shared__ short H1s[64 * 128];              // 16 KB
    __shared__ unsigned short msgt[64][136];     // 17 KB bf16 message tile (+16B pad)
    __shared__ int dsts[64];
    __shared__ unsigned long long maskS;
    const int tid  = threadIdx.x;
    const int lane = tid & 63;
    const int w    = tid >> 6;     // wave id = filter block
    const int q    = lane >> 4;
    const int m    = lane & 15;

    bf16x8 W1R[2], W2R[4];
    #pragma unroll
    for (int kc = 0; kc < 2; ++kc) {
        bf16x8 f;
        #pragma unroll
        for (int j = 0; j < 8; ++j) {
            int k = kc * 32 + q * 8 + j;
            float v = (k < NG) ? W1[k * NF + w * 16 + m] : 0.0f;  // pad G 50->64
            f[j] = f2bf(v);
        }
        W1R[kc] = f;
    }
    #pragma unroll
    for (int kc = 0; kc < 4; ++kc) {
        bf16x8 f;
        #pragma unroll
        for (int j = 0; j < 8; ++j) {
            int k = kc * 32 + q * 8 + j;
            f[j] = f2bf(W2[k * NF + w * 16 + m]);
        }
        W2R[kc] = f;
    }
    const float b1v = b1[w * 16 + m];
    const float b2v = b2[w * 16 + m];

    const int nrounds = N_EDGES / 64;
    for (int r = blockIdx.x; r < nrounds; r += gridDim.x) {
        const int p0 = r * 64;
        short* H = H1s;

        // ---- matvec1: A from precomputed rbfF + ssp + swizzled H1 store ----
        #pragma unroll
        for (int a = 0; a < 4; ++a) {
            int tile = r * 4 + a;
            f32x4 acc = {b1v, b1v, b1v, b1v};
            #pragma unroll
            for (int kc = 0; kc < 2; ++kc) {
                bf16x8 A = *(const bf16x8*)&rbfF[(size_t)((tile * 2 + kc) * 64 + lane) * 8];
                acc = __builtin_amdgcn_mfma_f32_16x16x32_bf16(A, W1R[kc], acc, 0, 0, 0);
            }
            #pragma unroll
            for (int i = 0; i < 4; ++i) {
                int e = a * 16 + q * 4 + i;
                int f = w * 16 + m;
                int byte = (e * 256 + f * 2) ^ ((e & 7) << 4);
                *(short*)((char*)H + byte) = f2bf(ssp_f(acc[i]));
            }
        }
        __syncthreads();   // A: H1 write -> read

        // ---- issue xj gathers now; they fly during matvec2 (T14 issue-early) ----
        unsigned short xu[4][4];
        #pragma unroll
        for (int a = 0; a < 4; ++a) {
            int4 s4 = *(const int4*)&srcS[p0 + a * 16 + q * 4];
            #pragma unroll
            for (int i = 0; i < 4; ++i)
                xu[a][i] = xjb[(size_t)((const int*)&s4)[i] * NF + w * 16 + m];
        }

        // ---- matvec2: Wf = H1 @ W2 + b2 ----
        f32x4 acc2[4];
        #pragma unroll
        for (int a = 0; a < 4; ++a) {
            f32x4 acc = {b2v, b2v, b2v, b2v};
            #pragma unroll
            for (int kc = 0; kc < 4; ++kc) {
                int e = a * 16 + m;
                int byte = (e * 256 + (kc * 32 + q * 8) * 2) ^ ((e & 7) << 4);
                bf16x8 A = *(const bf16x8*)((const char*)H + byte);  // ds_read_b128
                acc = __builtin_amdgcn_mfma_f32_16x16x32_bf16(A, W2R[kc], acc, 0, 0, 0);
            }
            acc2[a] = acc;
        }

        // ---- messages -> LDS tile (bf16): v = Wf * C * xv ----
        #pragma unroll
        for (int a = 0; a < 4; ++a) {
            float4 cc4 = *(const float4*)&CenvS[p0 + a * 16 + q * 4];
            #pragma unroll
            for (int i = 0; i < 4; ++i) {
                float v = acc2[a][i] * ((const float*)&cc4)[i];
                msgt[a * 16 + q * 4 + i][w * 16 + m] =
                    (unsigned short)f2bf(v * bf2f(xu[a][i]));
            }
        }
        if (w == 0) {
            int d = dstS[p0 + lane];
            int prev = __shfl_up(d, 1);
            bool head = (lane == 0) || (d != prev);
            unsigned long long mk = __ballot(head);
            dsts[lane] = d;
            if (lane == 0) maskS = mk;
        }
        __syncthreads();   // B: msgt/dsts write -> reduce

        // ---- run-segmented reduce: 128 threads x 4 run-groups, ILP-4 sums ----
        {
            int f = tid & 127;
            int g = tid >> 7;
            unsigned long long mm = maskS;
            int k = 0;
            while (mm) {
                int start = __ffsll(mm) - 1;
                mm &= mm - 1;
                int end = mm ? (__ffsll(mm) - 1) : 64;
                if ((k & 3) == g) {
                    float s0 = 0.0f, s1 = 0.0f, s2 = 0.0f, s3 = 0.0f;
                    int p = start;
                    for (; p + 4 <= end; p += 4) {   // 4 independent LDS chains
                        s0 += bf2f(msgt[p    ][f]);
                        s1 += bf2f(msgt[p + 1][f]);
                        s2 += bf2f(msgt[p + 2][f]);
                        s3 += bf2f(msgt[p + 3][f]);
                    }
                    for (; p < end; ++p) s0 += bf2f(msgt[p][f]);
                    float s = (s0 + s1) + (s2 + s3);
                    float* addr = &agg[(size_t)dsts[start] * NF + f];
                    if (start == 0 || end == 64) atomicAdd(addr, s);  // run may span rounds
                    else *addr = s;                                    // run exclusive here
                }
                ++k;
            }
        }
    }
}

// MFMA node GEMM: out[N,128] = post(in[N,128] @ W[128,128] + bias) (+ resid)
// 32-row tiles (grid = N/32 = 512 -> 2 blocks/CU) for latency overlap.
template<int ACT, int RESID, int OUTBF>
__global__ __launch_bounds__(512, 2)
void k_node_mfma(const float* __restrict__ in, const float* __restrict__ W,
                 const float* __restrict__ bias, const float* __restrict__ resid,
                 void* __restrict__ outv)
{
    __shared__ short T[32 * 128];   // 8 KB swizzled bf16 tile
    const int tid  = threadIdx.x;
    const int lane = tid & 63;
    const int w    = tid >> 6;
    const int q    = lane >> 4;
    const int m    = lane & 15;

    bf16x8 WR[4];
    #pragma unroll
    for (int kc = 0; kc < 4; ++kc) {
        bf16x8 f;
        #pragma unroll
        for (int j = 0; j < 8; ++j)
            f[j] = f2bf(W[(kc * 32 + q * 8 + j) * DIM + w * 16 + m]);
        WR[kc] = f;
    }
    const float bv = bias ? bias[w * 16 + m] : 0.0f;

    const int r0 = blockIdx.x * 32;

    // ---- stage: 32 rows x 128 k, f32 -> bf16, swizzled; 8 floats/thread ----
    {
        int row = tid >> 4;
        int k0  = (tid & 15) * 8;
        const float* src = in + (size_t)(r0 + row) * DIM + k0;
        float4 v0 = *(const float4*)(src);
        float4 v1 = *(const float4*)(src + 4);
        bf16x8 lo;
        #pragma unroll
        for (int j = 0; j < 4; ++j) {
            lo[j]     = f2bf(((const float*)&v0)[j]);
            lo[j + 4] = f2bf(((const float*)&v1)[j]);
        }
        int b0 = (row * 256 + k0 * 2) ^ ((row & 7) << 4);
        *(bf16x8*)((char*)T + b0) = lo;
    }
    __syncthreads();

    #pragma unroll
    for (int a = 0; a < 2; ++a) {
        f32x4 acc = {bv, bv, bv, bv};
        int row = a * 16 + m;
        #pragma unroll
        for (int kc = 0; kc < 4; ++kc) {
            int byte = (row * 256 + (kc * 32 + q * 8) * 2) ^ ((row & 7) << 4);
            bf16x8 A = *(const bf16x8*)((const char*)T + byte);
            acc = __builtin_amdgcn_mfma_f32_16x16x32_bf16(A, WR[kc], acc, 0, 0, 0);
        }
        #pragma unroll
        for (int i = 0; i < 4; ++i) {
            float v = acc[i];
            if (ACT) v = ssp_f(v);
            size_t oi = (size_t)(r0 + a * 16 + q * 4 + i) * DIM + w * 16 + m;
            if (RESID) v += resid[oi];
            if (OUTBF) ((unsigned short*)outv)[oi] = (unsigned short)f2bf(v);
            else       ((float*)outv)[oi] = v;
        }
    }
}

// fp32 node GEMM kept for lin1 (COLS=64)
template<int COLS, int ACT, int RESID>
__global__ __launch_bounds__(512)
void k_node_gemm(const float* __restrict__ in, const float* __restrict__ W,
                 const float* __restrict__ bias, const float* __restrict__ resid,
                 float* __restrict__ out)
{
    __shared__ float Ws[DIM][COLS];
    __shared__ float rs[EW][EB][DIM];
    int tid = threadIdx.x;
    for (int i = tid; i < DIM * COLS; i += 512) (&Ws[0][0])[i] = W[i];
    __syncthreads();

    int lane = tid & 63;
    int w = tid >> 6;
    int gw = blockIdx.x * EW + w;
    int nw = gridDim.x * EW;
    int ngroups = N_ATOMS / EB;
    constexpr int CPL = COLS / 64;

    float bb[CPL];
    #pragma unroll
    for (int c = 0; c < CPL; ++c) bb[c] = bias ? bias[lane + 64 * c] : 0.0f;

    for (int grp = gw; grp < ngroups; grp += nw) {
        int r0 = grp * EB;
        #pragma unroll
        for (int r = 0; r < EB; ++r) {
            rs[w][r][lane]      = in[(size_t)(r0 + r) * DIM + lane];
            rs[w][r][lane + 64] = in[(size_t)(r0 + r) * DIM + lane + 64];
        }
        float acc[EB][CPL];
        #pragma unroll
        for (int r = 0; r < EB; ++r)
            #pragma unroll
            for (int c = 0; c < CPL; ++c) acc[r][c] = bb[c];
        #pragma unroll 2
        for (int kb = 0; kb < DIM / 4; ++kb) {
            float4 rv[EB];
            #pragma unroll
            for (int r = 0; r < EB; ++r)
                rv[r] = *(const float4*)&rs[w][r][4 * kb];
            #pragma unroll
            for (int j = 0; j < 4; ++j) {
                float wv[CPL];
                #pragma unroll
                for (int c = 0; c < CPL; ++c) wv[c] = Ws[4 * kb + j][lane + 64 * c];
                #pragma unroll
                for (int r = 0; r < EB; ++r) {
                    float rj = ((const float*)&rv[r])[j];
                    #pragma unroll
                    for (int c = 0; c < CPL; ++c)
                        acc[r][c] = fmaf(rj, wv[c], acc[r][c]);
                }
            }
        }
        #pragma unroll
        for (int r = 0; r < EB; ++r) {
            #pragma unroll
            for (int c = 0; c < CPL; ++c) {
                float v = acc[r][c];
                if (ACT) v = ssp_f(v);
                size_t oi = (size_t)(r0 + r) * COLS + lane + 64 * c;
                if (RESID) v += resid[oi];
                out[oi] = v;
            }
        }
    }
}

// per-atom: dot(r1[n], lin2W) + lin2b -> per-block LDS mol reduce -> 32 atomics
__global__ __launch_bounds__(256)
void k_final(const float* __restrict__ r1, const float* __restrict__ l2W,
             const float* __restrict__ l2b, const int* __restrict__ batch,
             float* __restrict__ out)
{
    __shared__ float mols[NMOLS];
    int tid = threadIdx.x;
    if (tid < NMOLS) mols[tid] = 0.0f;
    __syncthreads();

    int n = blockIdx.x * 256 + tid;
    const float4* row = (const float4*)(r1 + (size_t)n * 64);
    const float4* wv  = (const float4*)l2W;
    float s = 0.0f;
    #pragma unroll
    for (int k = 0; k < 16; ++k) {
        float4 a = row[k], b = wv[k];
        s += a.x * b.x + a.y * b.y + a.z * b.z + a.w * b.w;
    }
    s += l2b[0];
    atomicAdd(&mols[batch[n]], s);   // LDS atomic (block-local)
    __syncthreads();
    if (tid < NMOLS) atomicAdd(&out[tid], mols[tid]);
}

extern "C" void kernel_launch(void* const* d_in, const int* in_sizes, int n_in,
                              void* d_out, int out_size, void* d_ws, size_t ws_size,
                              hipStream_t stream) {
    const float* z     = (const float*)d_in[0];
    const float* pos   = (const float*)d_in[1];
    const int*   batch = (const int*)d_in[2];
    const int*   esrc  = (const int*)d_in[3];
    const int*   edst  = (const int*)d_in[4];
    const float* embW  = (const float*)d_in[5];
    const float* embB  = (const float*)d_in[6];
    const float* mlpW1 = (const float*)d_in[7];
    const float* mlpB1 = (const float*)d_in[8];
    const float* mlpW2 = (const float*)d_in[9];
    const float* mlpB2 = (const float*)d_in[10];
    const float* cf1W  = (const float*)d_in[11];
    const float* cf2W  = (const float*)d_in[12];
    const float* cf2B  = (const float*)d_in[13];
    const float* intW  = (const float*)d_in[14];
    const float* intB  = (const float*)d_in[15];
    const float* l1W   = (const float*)d_in[16];
    const float* l1B   = (const float*)d_in[17];
    const float* l2W   = (const float*)d_in[18];
    const float* l2B   = (const float*)d_in[19];
    float* out = (float*)d_out;

    char* ws = (char*)d_ws;
    float* h     = (float*)(ws);                        // 8 MB
    float* dist  = (float*)(ws + (size_t)( 8 << 20));   // 1 MB
    float* Cv    = (float*)(ws + (size_t)( 9 << 20));   // 1 MB
    unsigned short* xj = (unsigned short*)(ws + (size_t)(10 << 20)); // 4 MB bf16
    float* tbuf  = (float*)(ws + (size_t)(10 << 20));   // 8 MB (aliases xj; liveness-disjoint)
    float* agg   = (float*)(ws + (size_t)(18 << 20));   // 8 MB (reused as r1)
    short* rbfF  = (short*)(ws + (size_t)(26 << 20));   // 32 MB bf16 A-fragments
    int*   deg   = (int*)  (ws + (size_t)(58 << 20));   // 64 KB
    int*   cur   = (int*)  (ws + (size_t)(59 << 20));   // 64 KB
    int*   edge_of = (int*)(ws + (size_t)(60 << 20));   // 1 MB
    float* distS = (float*)(ws + (size_t)(61 << 20));   // 1 MB
    float* CenvS = (float*)(ws + (size_t)(62 << 20));   // 1 MB
    int*   srcS  = (int*)  (ws + (size_t)(63 << 20));   // 1 MB
    int*   dstS  = (int*)  (ws + (size_t)(64 << 20));   // 1 MB
    float* r1    = agg;

    k_embed<<<dim3(N_ATOMS * DIM / 512), dim3(512), 0, stream>>>(z, embW, embB, h);
    k_geom<<<dim3(N_EDGES / 256), dim3(256), 0, stream>>>(pos, esrc, edst, dist, Cv);

    // CSR build (dst-sorted slot permutation)
    hipMemsetAsync(deg, 0, N_ATOMS * sizeof(int), stream);
    k_deg<<<dim3(N_EDGES / 512), dim3(512), 0, stream>>>(edst, deg);
    k_scan<<<dim3(1), dim3(1024), 0, stream>>>(deg, cur);
    k_fill<<<dim3(N_EDGES / 512), dim3(512), 0, stream>>>(edst, cur, edge_of);
    k_perm<<<dim3(N_EDGES / 512), dim3(512), 0, stream>>>(edge_of, dist, Cv, esrc, edst,
                                                          distS, CenvS, srcS, dstS);
    k_rbf<<<dim3(N_EDGES / 16 / 8), dim3(512), 0, stream>>>(distS, rbfF);

    for (int l = 0; l < NL; ++l) {
        // cf1: h @ cf1W -> xj (bf16 out). tbuf (aliased) is dead here.
        k_node_mfma<0, 0, 1><<<dim3(N_ATOMS / 32), dim3(512), 0, stream>>>(
            h, cf1W + (size_t)l * DIM * NF, nullptr, nullptr, (void*)xj);
        hipMemsetAsync(agg, 0, (size_t)N_ATOMS * NF * sizeof(float), stream);
        k_edge_csr<<<dim3(1024), dim3(512), 0, stream>>>(
            rbfF, CenvS, srcS, dstS,
            mlpW1 + (size_t)l * NG * NF, mlpB1 + (size_t)l * NF,
            mlpW2 + (size_t)l * NF * NF, mlpB2 + (size_t)l * NF,
            xj, agg);
        // cf2: ssp(agg @ cf2W + b) -> tbuf (xj dead now; alias safe)
        k_node_mfma<1, 0, 0><<<dim3(N_ATOMS / 32), dim3(512), 0, stream>>>(
            agg, cf2W + (size_t)l * NF * DIM, cf2B + (size_t)l * DIM, nullptr, (void*)tbuf);
        // int_lin: tbuf @ intW + b + h -> h
        k_node_mfma<0, 1, 0><<<dim3(N_ATOMS / 32), dim3(512), 0, stream>>>(
            tbuf, intW + (size_t)l * DIM * DIM, intB + (size_t)l * DIM, h, (void*)h);
    }

    k_node_gemm<64, 1, 0><<<dim3(256), dim3(512), 0, stream>>>(h, l1W, l1B, nullptr, r1);
    hipMemsetAsync(out, 0, NMOLS * sizeof(float), stream);
    k_final<<<dim3(N_ATOMS / 256), dim3(256), 0, stream>>>(r1, l2W, l2B, batch, out);
}

// Round 13
// 482.847 us; speedup vs baseline: 1.8080x; 1.0559x over previous
//
#include <hip/hip_runtime.h>
#include <hip/hip_bf16.h>
#include <math.h>

#define N_ATOMS 16384
#define N_EDGES 262144
#define DIM 128
#define NF 128
#define NG 50
#define NL 4
#define NMOLS 32
#define EW 8   // waves per block
#define EB 4   // rows per wave batch (fp32 node gemm)

typedef short bf16x8 __attribute__((ext_vector_type(8)));
typedef float f32x4 __attribute__((ext_vector_type(4)));

__device__ __forceinline__ float ssp_f(float x) {
    // softplus(x) - log(2) = max(x,0) + log(1 + exp(-|x|)) - log(2)
    float e = __expf(-fabsf(x));
    return fmaxf(x, 0.0f) + __logf(1.0f + e) - 0.6931471805599453f;
}

__device__ __forceinline__ short f2bf(float x) {
    __hip_bfloat16 b = __float2bfloat16(x);  // RNE
    return *reinterpret_cast<short*>(&b);
}

__device__ __forceinline__ float bf2f(unsigned short u) {
    unsigned int v = ((unsigned int)u) << 16;
    return __builtin_bit_cast(float, v);
}

// h[n][d] = z[n]*emb_W[d] + emb_b[d]
__global__ void k_embed(const float* __restrict__ z, const float* __restrict__ Wv,
                        const float* __restrict__ bv, float* __restrict__ h) {
    int idx = blockIdx.x * blockDim.x + threadIdx.x;
    int n = idx >> 7, d = idx & 127;
    h[idx] = z[n] * Wv[d] + bv[d];
}

// dist[e], C[e]
__global__ void k_geom(const float* __restrict__ pos, const int* __restrict__ src,
                       const int* __restrict__ dst, float* __restrict__ dist,
                       float* __restrict__ Cenv) {
    int e = blockIdx.x * blockDim.x + threadIdx.x;
    if (e >= N_EDGES) return;
    int s = src[e], t = dst[e];
    float dx = pos[3*s]   - pos[3*t];
    float dy = pos[3*s+1] - pos[3*t+1];
    float dz = pos[3*s+2] - pos[3*t+2];
    float d = sqrtf(dx*dx + dy*dy + dz*dz + 1e-12f);
    dist[e] = d;
    Cenv[e] = 0.5f * (cosf(d * (float)(M_PI / 5.0)) + 1.0f);
}

// ---- CSR build: sort edges by dst via counting sort ----
__global__ void k_deg(const int* __restrict__ dst, int* __restrict__ deg) {
    int e = blockIdx.x * blockDim.x + threadIdx.x;
    if (e < N_EDGES) atomicAdd(&deg[dst[e]], 1);
}

__global__ __launch_bounds__(1024)
void k_scan(const int* __restrict__ deg, int* __restrict__ cur) {
    __shared__ int tot[1024];
    int t = threadIdx.x;
    int v[16];
    int s = 0;
    #pragma unroll
    for (int j = 0; j < 16; ++j) { int x = deg[t * 16 + j]; v[j] = s; s += x; }
    tot[t] = s;
    __syncthreads();
    for (int off = 1; off < 1024; off <<= 1) {
        int add = (t >= off) ? tot[t - off] : 0;
        __syncthreads();
        tot[t] += add;
        __syncthreads();
    }
    int base = (t == 0) ? 0 : tot[t - 1];
    #pragma unroll
    for (int j = 0; j < 16; ++j) cur[t * 16 + j] = base + v[j];
}

__global__ void k_fill(const int* __restrict__ dst, int* __restrict__ cur,
                       int* __restrict__ edge_of) {
    int e = blockIdx.x * blockDim.x + threadIdx.x;
    if (e < N_EDGES) {
        int p = atomicAdd(&cur[dst[e]], 1);
        edge_of[p] = e;
    }
}

__global__ void k_perm(const int* __restrict__ edge_of, const float* __restrict__ dist,
                       const float* __restrict__ Cenv, const int* __restrict__ src,
                       const int* __restrict__ dst, float* __restrict__ distS,
                       float* __restrict__ CenvS, int* __restrict__ srcS,
                       int* __restrict__ dstS) {
    int p = blockIdx.x * blockDim.x + threadIdx.x;
    if (p >= N_EDGES) return;
    int e = edge_of[p];
    distS[p] = dist[e];
    CenvS[p] = Cenv[e];
    srcS[p]  = src[e];
    dstS[p]  = dst[e];
}

// Precompute rbf in MFMA A-fragment layout, SLOT order (layer-invariant, used 4x).
__global__ __launch_bounds__(512)
void k_rbf(const float* __restrict__ distS, short* __restrict__ rbfF) {
    int lane = threadIdx.x & 63;
    int w    = threadIdx.x >> 6;
    int t    = blockIdx.x * 8 + w;            // tile = 16 slots
    int q = lane >> 4, m = lane & 15;
    float d = distS[t * 16 + m];
    #pragma unroll
    for (int kc = 0; kc < 2; ++kc) {
        bf16x8 v;
        #pragma unroll
        for (int j = 0; j < 8; ++j) {
            float mu = (float)(kc * 32 + q * 8 + j) * (5.0f / 49.0f);
            float tt = d - mu;
            v[j] = f2bf(__expf(-4.0f * tt * tt));   // k>=50 rows hit zero W1R
        }
        *(bf16x8*)&rbfF[(size_t)((t * 2 + kc) * 64 + lane) * 8] = v;
    }
}

// MFMA edge pipeline over dst-sorted slots (r12 structure, unchanged).
__global__ __launch_bounds__(512, 4)
void k_edge_csr(const short* __restrict__ rbfF, const float* __restrict__ CenvS,
                const int* __restrict__ srcS, const int* __restrict__ dstS,
                const float* __restrict__ W1, const float* __restrict__ b1,
                const float* __restrict__ W2, const float* __restrict__ b2,
                const unsigned short* __restrict__ xjb, float* __restrict__ agg)
{
    __shared__ short H1s[64 * 128];              // 16 KB
    __shared__ unsigned short msgt[64][136];     // 17 KB bf16 message tile (+16B pad)
    __shared__ int dsts[64];
    __shared__ unsigned long long maskS;
    const int tid  = threadIdx.x;
    const int lane = tid & 63;
    const int w    = tid >> 6;     // wave id = filter block
    const int q    = lane >> 4;
    const int m    = lane & 15;

    bf16x8 W1R[2], W2R[4];
    #pragma unroll
    for (int kc = 0; kc < 2; ++kc) {
        bf16x8 f;
        #pragma unroll
        for (int j = 0; j < 8; ++j) {
            int k = kc * 32 + q * 8 + j;
            float v = (k < NG) ? W1[k * NF + w * 16 + m] : 0.0f;  // pad G 50->64
            f[j] = f2bf(v);
        }
        W1R[kc] = f;
    }
    #pragma unroll
    for (int kc = 0; kc < 4; ++kc) {
        bf16x8 f;
        #pragma unroll
        for (int j = 0; j < 8; ++j) {
            int k = kc * 32 + q * 8 + j;
            f[j] = f2bf(W2[k * NF + w * 16 + m]);
        }
        W2R[kc] = f;
    }
    const float b1v = b1[w * 16 + m];
    const float b2v = b2[w * 16 + m];

    const int nrounds = N_EDGES / 64;
    for (int r = blockIdx.x; r < nrounds; r += gridDim.x) {
        const int p0 = r * 64;
        short* H = H1s;

        // ---- matvec1: A from precomputed rbfF + ssp + swizzled H1 store ----
        #pragma unroll
        for (int a = 0; a < 4; ++a) {
            int tile = r * 4 + a;
            f32x4 acc = {b1v, b1v, b1v, b1v};
            #pragma unroll
            for (int kc = 0; kc < 2; ++kc) {
                bf16x8 A = *(const bf16x8*)&rbfF[(size_t)((tile * 2 + kc) * 64 + lane) * 8];
                acc = __builtin_amdgcn_mfma_f32_16x16x32_bf16(A, W1R[kc], acc, 0, 0, 0);
            }
            #pragma unroll
            for (int i = 0; i < 4; ++i) {
                int e = a * 16 + q * 4 + i;
                int f = w * 16 + m;
                int byte = (e * 256 + f * 2) ^ ((e & 7) << 4);
                *(short*)((char*)H + byte) = f2bf(ssp_f(acc[i]));
            }
        }
        __syncthreads();   // A: H1 write -> read

        // ---- issue xj gathers now; they fly during matvec2 (T14 issue-early) ----
        unsigned short xu[4][4];
        #pragma unroll
        for (int a = 0; a < 4; ++a) {
            int4 s4 = *(const int4*)&srcS[p0 + a * 16 + q * 4];
            #pragma unroll
            for (int i = 0; i < 4; ++i)
                xu[a][i] = xjb[(size_t)((const int*)&s4)[i] * NF + w * 16 + m];
        }

        // ---- matvec2: Wf = H1 @ W2 + b2 ----
        f32x4 acc2[4];
        #pragma unroll
        for (int a = 0; a < 4; ++a) {
            f32x4 acc = {b2v, b2v, b2v, b2v};
            #pragma unroll
            for (int kc = 0; kc < 4; ++kc) {
                int e = a * 16 + m;
                int byte = (e * 256 + (kc * 32 + q * 8) * 2) ^ ((e & 7) << 4);
                bf16x8 A = *(const bf16x8*)((const char*)H + byte);  // ds_read_b128
                acc = __builtin_amdgcn_mfma_f32_16x16x32_bf16(A, W2R[kc], acc, 0, 0, 0);
            }
            acc2[a] = acc;
        }

        // ---- messages -> LDS tile (bf16): v = Wf * C * xv ----
        #pragma unroll
        for (int a = 0; a < 4; ++a) {
            float4 cc4 = *(const float4*)&CenvS[p0 + a * 16 + q * 4];
            #pragma unroll
            for (int i = 0; i < 4; ++i) {
                float v = acc2[a][i] * ((const float*)&cc4)[i];
                msgt[a * 16 + q * 4 + i][w * 16 + m] =
                    (unsigned short)f2bf(v * bf2f(xu[a][i]));
            }
        }
        if (w == 0) {
            int d = dstS[p0 + lane];
            int prev = __shfl_up(d, 1);
            bool head = (lane == 0) || (d != prev);
            unsigned long long mk = __ballot(head);
            dsts[lane] = d;
            if (lane == 0) maskS = mk;
        }
        __syncthreads();   // B: msgt/dsts write -> reduce

        // ---- run-segmented reduce: 128 threads x 4 run-groups, ILP-4 sums ----
        {
            int f = tid & 127;
            int g = tid >> 7;
            unsigned long long mm = maskS;
            int k = 0;
            while (mm) {
                int start = __ffsll(mm) - 1;
                mm &= mm - 1;
                int end = mm ? (__ffsll(mm) - 1) : 64;
                if ((k & 3) == g) {
                    float s0 = 0.0f, s1 = 0.0f, s2 = 0.0f, s3 = 0.0f;
                    int p = start;
                    for (; p + 4 <= end; p += 4) {   // 4 independent LDS chains
                        s0 += bf2f(msgt[p    ][f]);
                        s1 += bf2f(msgt[p + 1][f]);
                        s2 += bf2f(msgt[p + 2][f]);
                        s3 += bf2f(msgt[p + 3][f]);
                    }
                    for (; p < end; ++p) s0 += bf2f(msgt[p][f]);
                    float s = (s0 + s1) + (s2 + s3);
                    float* addr = &agg[(size_t)dsts[start] * NF + f];
                    if (start == 0 || end == 64) atomicAdd(addr, s);  // run may span rounds
                    else *addr = s;                                    // run exclusive here
                }
                ++k;
            }
        }
    }
}

// MFMA node GEMM (single stage): out[N,128] = post(in @ W + bias); 32-row tiles.
template<int ACT, int RESID, int OUTBF>
__global__ __launch_bounds__(512, 2)
void k_node_mfma(const float* __restrict__ in, const float* __restrict__ W,
                 const float* __restrict__ bias, const float* __restrict__ resid,
                 void* __restrict__ outv)
{
    __shared__ short T[32 * 128];   // 8 KB swizzled bf16 tile
    const int tid  = threadIdx.x;
    const int lane = tid & 63;
    const int w    = tid >> 6;
    const int q    = lane >> 4;
    const int m    = lane & 15;

    bf16x8 WR[4];
    #pragma unroll
    for (int kc = 0; kc < 4; ++kc) {
        bf16x8 f;
        #pragma unroll
        for (int j = 0; j < 8; ++j)
            f[j] = f2bf(W[(kc * 32 + q * 8 + j) * DIM + w * 16 + m]);
        WR[kc] = f;
    }
    const float bv = bias ? bias[w * 16 + m] : 0.0f;

    const int r0 = blockIdx.x * 32;

    {
        int row = tid >> 4;
        int k0  = (tid & 15) * 8;
        const float* src = in + (size_t)(r0 + row) * DIM + k0;
        float4 v0 = *(const float4*)(src);
        float4 v1 = *(const float4*)(src + 4);
        bf16x8 lo;
        #pragma unroll
        for (int j = 0; j < 4; ++j) {
            lo[j]     = f2bf(((const float*)&v0)[j]);
            lo[j + 4] = f2bf(((const float*)&v1)[j]);
        }
        int b0 = (row * 256 + k0 * 2) ^ ((row & 7) << 4);
        *(bf16x8*)((char*)T + b0) = lo;
    }
    __syncthreads();

    #pragma unroll
    for (int a = 0; a < 2; ++a) {
        f32x4 acc = {bv, bv, bv, bv};
        int row = a * 16 + m;
        #pragma unroll
        for (int kc = 0; kc < 4; ++kc) {
            int byte = (row * 256 + (kc * 32 + q * 8) * 2) ^ ((row & 7) << 4);
            bf16x8 A = *(const bf16x8*)((const char*)T + byte);
            acc = __builtin_amdgcn_mfma_f32_16x16x32_bf16(A, WR[kc], acc, 0, 0, 0);
        }
        #pragma unroll
        for (int i = 0; i < 4; ++i) {
            float v = acc[i];
            if (ACT) v = ssp_f(v);
            size_t oi = (size_t)(r0 + a * 16 + q * 4 + i) * DIM + w * 16 + m;
            if (RESID) v += resid[oi];
            if (OUTBF) ((unsigned short*)outv)[oi] = (unsigned short)f2bf(v);
            else       ((float*)outv)[oi] = v;
        }
    }
}

// Fused cf2 + int_lin: h += (ssp(agg @ W2 + b2)) @ Wi + bi.
// Two MFMA stages per 32-row tile; x transposed C/D->A-frag via swizzled LDS
// (same pattern as the edge kernel's H1). Saves the 8 MB tbuf roundtrip.
__global__ __launch_bounds__(512, 2)
void k_node_fused(const float* __restrict__ agg, const float* __restrict__ W2,
                  const float* __restrict__ b2, const float* __restrict__ Wi,
                  const float* __restrict__ bi, float* __restrict__ h)
{
    __shared__ short T[32 * 128];   // 8 KB input tile (swizzled bf16)
    __shared__ short X[32 * 128];   // 8 KB intermediate tile (swizzled bf16)
    const int tid  = threadIdx.x;
    const int lane = tid & 63;
    const int w    = tid >> 6;
    const int q    = lane >> 4;
    const int m    = lane & 15;

    bf16x8 W2R[4], WiR[4];
    #pragma unroll
    for (int kc = 0; kc < 4; ++kc) {
        bf16x8 f2v, fiv;
        #pragma unroll
        for (int j = 0; j < 8; ++j) {
            int k = kc * 32 + q * 8 + j;
            f2v[j] = f2bf(W2[k * DIM + w * 16 + m]);
            fiv[j] = f2bf(Wi[k * DIM + w * 16 + m]);
        }
        W2R[kc] = f2v;
        WiR[kc] = fiv;
    }
    const float b2v = b2[w * 16 + m];
    const float biv = bi[w * 16 + m];

    const int r0 = blockIdx.x * 32;

    // ---- stage agg tile -> T ----
    {
        int row = tid >> 4;
        int k0  = (tid & 15) * 8;
        const float* src = agg + (size_t)(r0 + row) * DIM + k0;
        float4 v0 = *(const float4*)(src);
        float4 v1 = *(const float4*)(src + 4);
        bf16x8 lo;
        #pragma unroll
        for (int j = 0; j < 4; ++j) {
            lo[j]     = f2bf(((const float*)&v0)[j]);
            lo[j + 4] = f2bf(((const float*)&v1)[j]);
        }
        int b0 = (row * 256 + k0 * 2) ^ ((row & 7) << 4);
        *(bf16x8*)((char*)T + b0) = lo;
    }
    __syncthreads();

    // ---- stage 1: x = ssp(T @ W2 + b2) -> X (transposed swizzled store) ----
    #pragma unroll
    for (int a = 0; a < 2; ++a) {
        f32x4 acc = {b2v, b2v, b2v, b2v};
        int row = a * 16 + m;
        #pragma unroll
        for (int kc = 0; kc < 4; ++kc) {
            int byte = (row * 256 + (kc * 32 + q * 8) * 2) ^ ((row & 7) << 4);
            bf16x8 A = *(const bf16x8*)((const char*)T + byte);
            acc = __builtin_amdgcn_mfma_f32_16x16x32_bf16(A, W2R[kc], acc, 0, 0, 0);
        }
        #pragma unroll
        for (int i = 0; i < 4; ++i) {
            int orow = a * 16 + q * 4 + i;      // C/D row
            int ocol = w * 16 + m;              // C/D col
            int byte = (orow * 256 + ocol * 2) ^ ((orow & 7) << 4);
            *(short*)((char*)X + byte) = f2bf(ssp_f(acc[i]));
        }
    }
    __syncthreads();

    // ---- stage 2: h += X @ Wi + bi ----
    #pragma unroll
    for (int a = 0; a < 2; ++a) {
        f32x4 acc = {biv, biv, biv, biv};
        int row = a * 16 + m;
        #pragma unroll
        for (int kc = 0; kc < 4; ++kc) {
            int byte = (row * 256 + (kc * 32 + q * 8) * 2) ^ ((row & 7) << 4);
            bf16x8 A = *(const bf16x8*)((const char*)X + byte);
            acc = __builtin_amdgcn_mfma_f32_16x16x32_bf16(A, WiR[kc], acc, 0, 0, 0);
        }
        #pragma unroll
        for (int i = 0; i < 4; ++i) {
            size_t oi = (size_t)(r0 + a * 16 + q * 4 + i) * DIM + w * 16 + m;
            h[oi] += acc[i];
        }
    }
}

// fp32 node GEMM kept for lin1 (COLS=64)
template<int COLS, int ACT, int RESID>
__global__ __launch_bounds__(512)
void k_node_gemm(const float* __restrict__ in, const float* __restrict__ W,
                 const float* __restrict__ bias, const float* __restrict__ resid,
                 float* __restrict__ out)
{
    __shared__ float Ws[DIM][COLS];
    __shared__ float rs[EW][EB][DIM];
    int tid = threadIdx.x;
    for (int i = tid; i < DIM * COLS; i += 512) (&Ws[0][0])[i] = W[i];
    __syncthreads();

    int lane = tid & 63;
    int w = tid >> 6;
    int gw = blockIdx.x * EW + w;
    int nw = gridDim.x * EW;
    int ngroups = N_ATOMS / EB;
    constexpr int CPL = COLS / 64;

    float bb[CPL];
    #pragma unroll
    for (int c = 0; c < CPL; ++c) bb[c] = bias ? bias[lane + 64 * c] : 0.0f;

    for (int grp = gw; grp < ngroups; grp += nw) {
        int r0 = grp * EB;
        #pragma unroll
        for (int r = 0; r < EB; ++r) {
            rs[w][r][lane]      = in[(size_t)(r0 + r) * DIM + lane];
            rs[w][r][lane + 64] = in[(size_t)(r0 + r) * DIM + lane + 64];
        }
        float acc[EB][CPL];
        #pragma unroll
        for (int r = 0; r < EB; ++r)
            #pragma unroll
            for (int c = 0; c < CPL; ++c) acc[r][c] = bb[c];
        #pragma unroll 2
        for (int kb = 0; kb < DIM / 4; ++kb) {
            float4 rv[EB];
            #pragma unroll
            for (int r = 0; r < EB; ++r)
                rv[r] = *(const float4*)&rs[w][r][4 * kb];
            #pragma unroll
            for (int j = 0; j < 4; ++j) {
                float wv[CPL];
                #pragma unroll
                for (int c = 0; c < CPL; ++c) wv[c] = Ws[4 * kb + j][lane + 64 * c];
                #pragma unroll
                for (int r = 0; r < EB; ++r) {
                    float rj = ((const float*)&rv[r])[j];
                    #pragma unroll
                    for (int c = 0; c < CPL; ++c)
                        acc[r][c] = fmaf(rj, wv[c], acc[r][c]);
                }
            }
        }
        #pragma unroll
        for (int r = 0; r < EB; ++r) {
            #pragma unroll
            for (int c = 0; c < CPL; ++c) {
                float v = acc[r][c];
                if (ACT) v = ssp_f(v);
                size_t oi = (size_t)(r0 + r) * COLS + lane + 64 * c;
                if (RESID) v += resid[oi];
                out[oi] = v;
            }
        }
    }
}

// per-atom: dot(r1[n], lin2W) + lin2b -> per-block LDS mol reduce -> 32 atomics
__global__ __launch_bounds__(256)
void k_final(const float* __restrict__ r1, const float* __restrict__ l2W,
             const float* __restrict__ l2b, const int* __restrict__ batch,
             float* __restrict__ out)
{
    __shared__ float mols[NMOLS];
    int tid = threadIdx.x;
    if (tid < NMOLS) mols[tid] = 0.0f;
    __syncthreads();

    int n = blockIdx.x * 256 + tid;
    const float4* row = (const float4*)(r1 + (size_t)n * 64);
    const float4* wv  = (const float4*)l2W;
    float s = 0.0f;
    #pragma unroll
    for (int k = 0; k < 16; ++k) {
        float4 a = row[k], b = wv[k];
        s += a.x * b.x + a.y * b.y + a.z * b.z + a.w * b.w;
    }
    s += l2b[0];
    atomicAdd(&mols[batch[n]], s);   // LDS atomic (block-local)
    __syncthreads();
    if (tid < NMOLS) atomicAdd(&out[tid], mols[tid]);
}

extern "C" void kernel_launch(void* const* d_in, const int* in_sizes, int n_in,
                              void* d_out, int out_size, void* d_ws, size_t ws_size,
                              hipStream_t stream) {
    const float* z     = (const float*)d_in[0];
    const float* pos   = (const float*)d_in[1];
    const int*   batch = (const int*)d_in[2];
    const int*   esrc  = (const int*)d_in[3];
    const int*   edst  = (const int*)d_in[4];
    const float* embW  = (const float*)d_in[5];
    const float* embB  = (const float*)d_in[6];
    const float* mlpW1 = (const float*)d_in[7];
    const float* mlpB1 = (const float*)d_in[8];
    const float* mlpW2 = (const float*)d_in[9];
    const float* mlpB2 = (const float*)d_in[10];
    const float* cf1W  = (const float*)d_in[11];
    const float* cf2W  = (const float*)d_in[12];
    const float* cf2B  = (const float*)d_in[13];
    const float* intW  = (const float*)d_in[14];
    const float* intB  = (const float*)d_in[15];
    const float* l1W   = (const float*)d_in[16];
    const float* l1B   = (const float*)d_in[17];
    const float* l2W   = (const float*)d_in[18];
    const float* l2B   = (const float*)d_in[19];
    float* out = (float*)d_out;

    char* ws = (char*)d_ws;
    float* h     = (float*)(ws);                        // 8 MB
    float* dist  = (float*)(ws + (size_t)( 8 << 20));   // 1 MB
    float* Cv    = (float*)(ws + (size_t)( 9 << 20));   // 1 MB
    unsigned short* xj = (unsigned short*)(ws + (size_t)(10 << 20)); // 4 MB bf16
    float* agg   = (float*)(ws + (size_t)(18 << 20));   // 8 MB (reused as r1)
    short* rbfF  = (short*)(ws + (size_t)(26 << 20));   // 32 MB bf16 A-fragments
    int*   deg   = (int*)  (ws + (size_t)(58 << 20));   // 64 KB
    int*   cur   = (int*)  (ws + (size_t)(59 << 20));   // 64 KB
    int*   edge_of = (int*)(ws + (size_t)(60 << 20));   // 1 MB
    float* distS = (float*)(ws + (size_t)(61 << 20));   // 1 MB
    float* CenvS = (float*)(ws + (size_t)(62 << 20));   // 1 MB
    int*   srcS  = (int*)  (ws + (size_t)(63 << 20));   // 1 MB
    int*   dstS  = (int*)  (ws + (size_t)(64 << 20));   // 1 MB
    float* r1    = agg;

    k_embed<<<dim3(N_ATOMS * DIM / 512), dim3(512), 0, stream>>>(z, embW, embB, h);
    k_geom<<<dim3(N_EDGES / 256), dim3(256), 0, stream>>>(pos, esrc, edst, dist, Cv);

    // CSR build (dst-sorted slot permutation)
    hipMemsetAsync(deg, 0, N_ATOMS * sizeof(int), stream);
    k_deg<<<dim3(N_EDGES / 512), dim3(512), 0, stream>>>(edst, deg);
    k_scan<<<dim3(1), dim3(1024), 0, stream>>>(deg, cur);
    k_fill<<<dim3(N_EDGES / 512), dim3(512), 0, stream>>>(edst, cur, edge_of);
    k_perm<<<dim3(N_EDGES / 512), dim3(512), 0, stream>>>(edge_of, dist, Cv, esrc, edst,
                                                          distS, CenvS, srcS, dstS);
    k_rbf<<<dim3(N_EDGES / 16 / 8), dim3(512), 0, stream>>>(distS, rbfF);

    for (int l = 0; l < NL; ++l) {
        // cf1: h @ cf1W -> xj (bf16 out)
        k_node_mfma<0, 0, 1><<<dim3(N_ATOMS / 32), dim3(512), 0, stream>>>(
            h, cf1W + (size_t)l * DIM * NF, nullptr, nullptr, (void*)xj);
        hipMemsetAsync(agg, 0, (size_t)N_ATOMS * NF * sizeof(float), stream);
        k_edge_csr<<<dim3(1024), dim3(512), 0, stream>>>(
            rbfF, CenvS, srcS, dstS,
            mlpW1 + (size_t)l * NG * NF, mlpB1 + (size_t)l * NF,
            mlpW2 + (size_t)l * NF * NF, mlpB2 + (size_t)l * NF,
            xj, agg);
        // fused cf2 + int_lin: h += ssp(agg@cf2W+b) @ intW + b
        k_node_fused<<<dim3(N_ATOMS / 32), dim3(512), 0, stream>>>(
            agg, cf2W + (size_t)l * NF * DIM, cf2B + (size_t)l * DIM,
            intW + (size_t)l * DIM * DIM, intB + (size_t)l * DIM, h);
    }

    k_node_gemm<64, 1, 0><<<dim3(256), dim3(512), 0, stream>>>(h, l1W, l1B, nullptr, r1);
    hipMemsetAsync(out, 0, NMOLS * sizeof(float), stream);
    k_final<<<dim3(N_ATOMS / 256), dim3(256), 0, stream>>>(r1, l2W, l2B, batch, out);
}

// Round 14
// 463.579 us; speedup vs baseline: 1.8832x; 1.0416x over previous
//
#include <hip/hip_runtime.h>
#include <hip/hip_bf16.h>
#include <math.h>

#define N_ATOMS 16384
#define N_EDGES 262144
#define DIM 128
#define NF 128
#define NG 50
#define NL 4
#define NMOLS 32
#define EW 8   // waves per block
#define EB 4   // rows per wave batch (fp32 node gemm)

typedef short bf16x8 __attribute__((ext_vector_type(8)));
typedef float f32x4 __attribute__((ext_vector_type(4)));

__device__ __forceinline__ float ssp_f(float x) {
    // softplus(x) - log(2) = max(x,0) + log(1 + exp(-|x|)) - log(2)
    float e = __expf(-fabsf(x));
    return fmaxf(x, 0.0f) + __logf(1.0f + e) - 0.6931471805599453f;
}

__device__ __forceinline__ short f2bf(float x) {
    __hip_bfloat16 b = __float2bfloat16(x);  // RNE
    return *reinterpret_cast<short*>(&b);
}

__device__ __forceinline__ float bf2f(unsigned short u) {
    unsigned int v = ((unsigned int)u) << 16;
    return __builtin_bit_cast(float, v);
}

// Merged: h = z*emb_W + emb_b (all blocks) ; dist/Cenv (first 512 blocks)
__global__ __launch_bounds__(512)
void k_embed_geom(const float* __restrict__ z, const float* __restrict__ Wv,
                  const float* __restrict__ bv, float* __restrict__ h,
                  const float* __restrict__ pos, const int* __restrict__ src,
                  const int* __restrict__ dst, float* __restrict__ dist,
                  float* __restrict__ Cenv) {
    int idx = blockIdx.x * 512 + threadIdx.x;
    int n = idx >> 7, d = idx & 127;
    h[idx] = z[n] * Wv[d] + bv[d];
    if (blockIdx.x < N_EDGES / 512) {
        int e = blockIdx.x * 512 + threadIdx.x;
        int s = src[e], t = dst[e];
        float dx = pos[3*s]   - pos[3*t];
        float dy = pos[3*s+1] - pos[3*t+1];
        float dz = pos[3*s+2] - pos[3*t+2];
        float dd = sqrtf(dx*dx + dy*dy + dz*dz + 1e-12f);
        dist[e] = dd;
        Cenv[e] = 0.5f * (cosf(dd * (float)(M_PI / 5.0)) + 1.0f);
    }
}

// ---- CSR build: sort edges by dst via counting sort ----
__global__ void k_deg(const int* __restrict__ dst, int* __restrict__ deg) {
    int e = blockIdx.x * blockDim.x + threadIdx.x;
    if (e < N_EDGES) atomicAdd(&deg[dst[e]], 1);
}

__global__ __launch_bounds__(1024)
void k_scan(const int* __restrict__ deg, int* __restrict__ cur) {
    __shared__ int tot[1024];
    int t = threadIdx.x;
    int v[16];
    int s = 0;
    #pragma unroll
    for (int j = 0; j < 16; ++j) { int x = deg[t * 16 + j]; v[j] = s; s += x; }
    tot[t] = s;
    __syncthreads();
    for (int off = 1; off < 1024; off <<= 1) {
        int add = (t >= off) ? tot[t - off] : 0;
        __syncthreads();
        tot[t] += add;
        __syncthreads();
    }
    int base = (t == 0) ? 0 : tot[t - 1];
    #pragma unroll
    for (int j = 0; j < 16; ++j) cur[t * 16 + j] = base + v[j];
}

__global__ void k_fill(const int* __restrict__ dst, int* __restrict__ cur,
                       int* __restrict__ edge_of) {
    int e = blockIdx.x * blockDim.x + threadIdx.x;
    if (e < N_EDGES) {
        int p = atomicAdd(&cur[dst[e]], 1);
        edge_of[p] = e;
    }
}

__global__ void k_perm(const int* __restrict__ edge_of, const float* __restrict__ dist,
                       const float* __restrict__ Cenv, const int* __restrict__ src,
                       const int* __restrict__ dst, float* __restrict__ distS,
                       float* __restrict__ CenvS, int* __restrict__ srcS,
                       int* __restrict__ dstS) {
    int p = blockIdx.x * blockDim.x + threadIdx.x;
    if (p >= N_EDGES) return;
    int e = edge_of[p];
    distS[p] = dist[e];
    CenvS[p] = Cenv[e];
    srcS[p]  = src[e];
    dstS[p]  = dst[e];
}

// Precompute rbf in MFMA A-fragment layout, SLOT order (layer-invariant, used 4x).
__global__ __launch_bounds__(512)
void k_rbf(const float* __restrict__ distS, short* __restrict__ rbfF) {
    int lane = threadIdx.x & 63;
    int w    = threadIdx.x >> 6;
    int t    = blockIdx.x * 8 + w;            // tile = 16 slots
    int q = lane >> 4, m = lane & 15;
    float d = distS[t * 16 + m];
    #pragma unroll
    for (int kc = 0; kc < 2; ++kc) {
        bf16x8 v;
        #pragma unroll
        for (int j = 0; j < 8; ++j) {
            float mu = (float)(kc * 32 + q * 8 + j) * (5.0f / 49.0f);
            float tt = d - mu;
            v[j] = f2bf(__expf(-4.0f * tt * tt));   // k>=50 rows hit zero W1R
        }
        *(bf16x8*)&rbfF[(size_t)((t * 2 + kc) * 64 + lane) * 8] = v;
    }
}

// MFMA edge pipeline over dst-sorted slots (r12 structure, unchanged).
__global__ __launch_bounds__(512, 4)
void k_edge_csr(const short* __restrict__ rbfF, const float* __restrict__ CenvS,
                const int* __restrict__ srcS, const int* __restrict__ dstS,
                const float* __restrict__ W1, const float* __restrict__ b1,
                const float* __restrict__ W2, const float* __restrict__ b2,
                const unsigned short* __restrict__ xjb, float* __restrict__ agg)
{
    __shared__ short H1s[64 * 128];              // 16 KB
    __shared__ unsigned short msgt[64][136];     // 17 KB bf16 message tile (+16B pad)
    __shared__ int dsts[64];
    __shared__ unsigned long long maskS;
    const int tid  = threadIdx.x;
    const int lane = tid & 63;
    const int w    = tid >> 6;     // wave id = filter block
    const int q    = lane >> 4;
    const int m    = lane & 15;

    bf16x8 W1R[2], W2R[4];
    #pragma unroll
    for (int kc = 0; kc < 2; ++kc) {
        bf16x8 f;
        #pragma unroll
        for (int j = 0; j < 8; ++j) {
            int k = kc * 32 + q * 8 + j;
            float v = (k < NG) ? W1[k * NF + w * 16 + m] : 0.0f;  // pad G 50->64
            f[j] = f2bf(v);
        }
        W1R[kc] = f;
    }
    #pragma unroll
    for (int kc = 0; kc < 4; ++kc) {
        bf16x8 f;
        #pragma unroll
        for (int j = 0; j < 8; ++j) {
            int k = kc * 32 + q * 8 + j;
            f[j] = f2bf(W2[k * NF + w * 16 + m]);
        }
        W2R[kc] = f;
    }
    const float b1v = b1[w * 16 + m];
    const float b2v = b2[w * 16 + m];

    const int nrounds = N_EDGES / 64;
    for (int r = blockIdx.x; r < nrounds; r += gridDim.x) {
        const int p0 = r * 64;
        short* H = H1s;

        // ---- matvec1: A from precomputed rbfF + ssp + swizzled H1 store ----
        #pragma unroll
        for (int a = 0; a < 4; ++a) {
            int tile = r * 4 + a;
            f32x4 acc = {b1v, b1v, b1v, b1v};
            #pragma unroll
            for (int kc = 0; kc < 2; ++kc) {
                bf16x8 A = *(const bf16x8*)&rbfF[(size_t)((tile * 2 + kc) * 64 + lane) * 8];
                acc = __builtin_amdgcn_mfma_f32_16x16x32_bf16(A, W1R[kc], acc, 0, 0, 0);
            }
            #pragma unroll
            for (int i = 0; i < 4; ++i) {
                int e = a * 16 + q * 4 + i;
                int f = w * 16 + m;
                int byte = (e * 256 + f * 2) ^ ((e & 7) << 4);
                *(short*)((char*)H + byte) = f2bf(ssp_f(acc[i]));
            }
        }
        __syncthreads();   // A: H1 write -> read

        // ---- issue xj gathers now; they fly during matvec2 (T14 issue-early) ----
        unsigned short xu[4][4];
        #pragma unroll
        for (int a = 0; a < 4; ++a) {
            int4 s4 = *(const int4*)&srcS[p0 + a * 16 + q * 4];
            #pragma unroll
            for (int i = 0; i < 4; ++i)
                xu[a][i] = xjb[(size_t)((const int*)&s4)[i] * NF + w * 16 + m];
        }

        // ---- matvec2: Wf = H1 @ W2 + b2 ----
        f32x4 acc2[4];
        #pragma unroll
        for (int a = 0; a < 4; ++a) {
            f32x4 acc = {b2v, b2v, b2v, b2v};
            #pragma unroll
            for (int kc = 0; kc < 4; ++kc) {
                int e = a * 16 + m;
                int byte = (e * 256 + (kc * 32 + q * 8) * 2) ^ ((e & 7) << 4);
                bf16x8 A = *(const bf16x8*)((const char*)H + byte);  // ds_read_b128
                acc = __builtin_amdgcn_mfma_f32_16x16x32_bf16(A, W2R[kc], acc, 0, 0, 0);
            }
            acc2[a] = acc;
        }

        // ---- messages -> LDS tile (bf16): v = Wf * C * xv ----
        #pragma unroll
        for (int a = 0; a < 4; ++a) {
            float4 cc4 = *(const float4*)&CenvS[p0 + a * 16 + q * 4];
            #pragma unroll
            for (int i = 0; i < 4; ++i) {
                float v = acc2[a][i] * ((const float*)&cc4)[i];
                msgt[a * 16 + q * 4 + i][w * 16 + m] =
                    (unsigned short)f2bf(v * bf2f(xu[a][i]));
            }
        }
        if (w == 0) {
            int d = dstS[p0 + lane];
            int prev = __shfl_up(d, 1);
            bool head = (lane == 0) || (d != prev);
            unsigned long long mk = __ballot(head);
            dsts[lane] = d;
            if (lane == 0) maskS = mk;
        }
        __syncthreads();   // B: msgt/dsts write -> reduce

        // ---- run-segmented reduce: 128 threads x 4 run-groups, ILP-4 sums ----
        {
            int f = tid & 127;
            int g = tid >> 7;
            unsigned long long mm = maskS;
            int k = 0;
            while (mm) {
                int start = __ffsll(mm) - 1;
                mm &= mm - 1;
                int end = mm ? (__ffsll(mm) - 1) : 64;
                if ((k & 3) == g) {
                    float s0 = 0.0f, s1 = 0.0f, s2 = 0.0f, s3 = 0.0f;
                    int p = start;
                    for (; p + 4 <= end; p += 4) {   // 4 independent LDS chains
                        s0 += bf2f(msgt[p    ][f]);
                        s1 += bf2f(msgt[p + 1][f]);
                        s2 += bf2f(msgt[p + 2][f]);
                        s3 += bf2f(msgt[p + 3][f]);
                    }
                    for (; p < end; ++p) s0 += bf2f(msgt[p][f]);
                    float s = (s0 + s1) + (s2 + s3);
                    float* addr = &agg[(size_t)dsts[start] * NF + f];
                    if (start == 0 || end == 64) atomicAdd(addr, s);  // run may span rounds
                    else *addr = s;                                    // run exclusive here
                }
                ++k;
            }
        }
    }
}

// MFMA node GEMM (single stage): out = post(in @ W + bias); 32-row tiles.
// aggz != nullptr: also zero this block's rows of aggz (for the next edge pass).
template<int ACT, int RESID, int OUTBF>
__global__ __launch_bounds__(512, 2)
void k_node_mfma(const float* __restrict__ in, const float* __restrict__ W,
                 const float* __restrict__ bias, const float* __restrict__ resid,
                 void* __restrict__ outv, float* __restrict__ aggz)
{
    __shared__ short T[32 * 128];   // 8 KB swizzled bf16 tile
    const int tid  = threadIdx.x;
    const int lane = tid & 63;
    const int w    = tid >> 6;
    const int q    = lane >> 4;
    const int m    = lane & 15;

    bf16x8 WR[4];
    #pragma unroll
    for (int kc = 0; kc < 4; ++kc) {
        bf16x8 f;
        #pragma unroll
        for (int j = 0; j < 8; ++j)
            f[j] = f2bf(W[(kc * 32 + q * 8 + j) * DIM + w * 16 + m]);
        WR[kc] = f;
    }
    const float bv = bias ? bias[w * 16 + m] : 0.0f;

    const int r0 = blockIdx.x * 32;

    {
        int row = tid >> 4;
        int k0  = (tid & 15) * 8;
        const float* src = in + (size_t)(r0 + row) * DIM + k0;
        float4 v0 = *(const float4*)(src);
        float4 v1 = *(const float4*)(src + 4);
        bf16x8 lo;
        #pragma unroll
        for (int j = 0; j < 4; ++j) {
            lo[j]     = f2bf(((const float*)&v0)[j]);
            lo[j + 4] = f2bf(((const float*)&v1)[j]);
        }
        int b0 = (row * 256 + k0 * 2) ^ ((row & 7) << 4);
        *(bf16x8*)((char*)T + b0) = lo;
        if (aggz) {
            float4 zz = {0.0f, 0.0f, 0.0f, 0.0f};
            float* dz = aggz + (size_t)(r0 + row) * DIM + k0;
            *(float4*)dz = zz;
            *(float4*)(dz + 4) = zz;
        }
    }
    __syncthreads();

    #pragma unroll
    for (int a = 0; a < 2; ++a) {
        f32x4 acc = {bv, bv, bv, bv};
        int row = a * 16 + m;
        #pragma unroll
        for (int kc = 0; kc < 4; ++kc) {
            int byte = (row * 256 + (kc * 32 + q * 8) * 2) ^ ((row & 7) << 4);
            bf16x8 A = *(const bf16x8*)((const char*)T + byte);
            acc = __builtin_amdgcn_mfma_f32_16x16x32_bf16(A, WR[kc], acc, 0, 0, 0);
        }
        #pragma unroll
        for (int i = 0; i < 4; ++i) {
            float v = acc[i];
            if (ACT) v = ssp_f(v);
            size_t oi = (size_t)(r0 + a * 16 + q * 4 + i) * DIM + w * 16 + m;
            if (RESID) v += resid[oi];
            if (OUTBF) ((unsigned short*)outv)[oi] = (unsigned short)f2bf(v);
            else       ((float*)outv)[oi] = v;
        }
    }
}

// Fused cf2 + int_lin (+ next layer's cf1): per 32-row tile:
//   hn = h + ssp(agg @ W2 + b2) @ Wi + bi ; h = hn
//   EMIT: xjn = hn @ W1n (bf16), and zero this block's agg rows.
template<int EMIT>
__global__ __launch_bounds__(512, 2)
void k_node_fused(const float* __restrict__ agg, const float* __restrict__ W2,
                  const float* __restrict__ b2, const float* __restrict__ Wi,
                  const float* __restrict__ bi, float* __restrict__ h,
                  const float* __restrict__ W1n, unsigned short* __restrict__ xjn,
                  float* __restrict__ aggz)
{
    __shared__ short T[32 * 128];   // 8 KB: input tile, later hn^T tile
    __shared__ short X[32 * 128];   // 8 KB: intermediate tile
    const int tid  = threadIdx.x;
    const int lane = tid & 63;
    const int w    = tid >> 6;
    const int q    = lane >> 4;
    const int m    = lane & 15;

    bf16x8 W2R[4], WiR[4], W1nR[4];
    #pragma unroll
    for (int kc = 0; kc < 4; ++kc) {
        bf16x8 f2v, fiv;
        #pragma unroll
        for (int j = 0; j < 8; ++j) {
            int k = kc * 32 + q * 8 + j;
            f2v[j] = f2bf(W2[k * DIM + w * 16 + m]);
            fiv[j] = f2bf(Wi[k * DIM + w * 16 + m]);
        }
        W2R[kc] = f2v;
        WiR[kc] = fiv;
    }
    if constexpr (EMIT) {
        #pragma unroll
        for (int kc = 0; kc < 4; ++kc) {
            bf16x8 f;
            #pragma unroll
            for (int j = 0; j < 8; ++j)
                f[j] = f2bf(W1n[(kc * 32 + q * 8 + j) * DIM + w * 16 + m]);
            W1nR[kc] = f;
        }
    }
    const float b2v = b2[w * 16 + m];
    const float biv = bi[w * 16 + m];

    const int r0 = blockIdx.x * 32;
    const int srow = tid >> 4;
    const int sk0  = (tid & 15) * 8;

    // ---- stage agg tile -> T ----
    {
        const float* src = agg + (size_t)(r0 + srow) * DIM + sk0;
        float4 v0 = *(const float4*)(src);
        float4 v1 = *(const float4*)(src + 4);
        bf16x8 lo;
        #pragma unroll
        for (int j = 0; j < 4; ++j) {
            lo[j]     = f2bf(((const float*)&v0)[j]);
            lo[j + 4] = f2bf(((const float*)&v1)[j]);
        }
        int b0 = (srow * 256 + sk0 * 2) ^ ((srow & 7) << 4);
        *(bf16x8*)((char*)T + b0) = lo;
    }
    __syncthreads();   // bar1: T ready

    // ---- stage 1: X = ssp(T @ W2 + b2) (transposed swizzled store) ----
    #pragma unroll
    for (int a = 0; a < 2; ++a) {
        f32x4 acc = {b2v, b2v, b2v, b2v};
        int row = a * 16 + m;
        #pragma unroll
        for (int kc = 0; kc < 4; ++kc) {
            int byte = (row * 256 + (kc * 32 + q * 8) * 2) ^ ((row & 7) << 4);
            bf16x8 A = *(const bf16x8*)((const char*)T + byte);
            acc = __builtin_amdgcn_mfma_f32_16x16x32_bf16(A, W2R[kc], acc, 0, 0, 0);
        }
        #pragma unroll
        for (int i = 0; i < 4; ++i) {
            int orow = a * 16 + q * 4 + i;
            int ocol = w * 16 + m;
            int byte = (orow * 256 + ocol * 2) ^ ((orow & 7) << 4);
            *(short*)((char*)X + byte) = f2bf(ssp_f(acc[i]));
        }
    }
    __syncthreads();   // bar2: X ready; all T reads done (T now reusable)

    // ---- stage 2: hn = h + X @ Wi + bi; write h; stash hn^T into T ----
    #pragma unroll
    for (int a = 0; a < 2; ++a) {
        f32x4 acc = {biv, biv, biv, biv};
        int row = a * 16 + m;
        #pragma unroll
        for (int kc = 0; kc < 4; ++kc) {
            int byte = (row * 256 + (kc * 32 + q * 8) * 2) ^ ((row & 7) << 4);
            bf16x8 A = *(const bf16x8*)((const char*)X + byte);
            acc = __builtin_amdgcn_mfma_f32_16x16x32_bf16(A, WiR[kc], acc, 0, 0, 0);
        }
        #pragma unroll
        for (int i = 0; i < 4; ++i) {
            size_t oi = (size_t)(r0 + a * 16 + q * 4 + i) * DIM + w * 16 + m;
            float v = h[oi] + acc[i];
            h[oi] = v;
            if constexpr (EMIT) {
                int orow = a * 16 + q * 4 + i;
                int ocol = w * 16 + m;
                int byte = (orow * 256 + ocol * 2) ^ ((orow & 7) << 4);
                *(short*)((char*)T + byte) = f2bf(v);
            }
        }
    }

    if constexpr (EMIT) {
        // zero this block's agg rows for the next edge pass (reads done pre-bar1)
        {
            float4 zz = {0.0f, 0.0f, 0.0f, 0.0f};
            float* dz = aggz + (size_t)(r0 + srow) * DIM + sk0;
            *(float4*)dz = zz;
            *(float4*)(dz + 4) = zz;
        }
        __syncthreads();   // bar3: hn^T tile ready

        // ---- stage 3: xjn = hn @ W1n (no bias) ----
        #pragma unroll
        for (int a = 0; a < 2; ++a) {
            f32x4 acc = {0.0f, 0.0f, 0.0f, 0.0f};
            int row = a * 16 + m;
            #pragma unroll
            for (int kc = 0; kc < 4; ++kc) {
                int byte = (row * 256 + (kc * 32 + q * 8) * 2) ^ ((row & 7) << 4);
                bf16x8 A = *(const bf16x8*)((const char*)T + byte);
                acc = __builtin_amdgcn_mfma_f32_16x16x32_bf16(A, W1nR[kc], acc, 0, 0, 0);
            }
            #pragma unroll
            for (int i = 0; i < 4; ++i) {
                size_t oi = (size_t)(r0 + a * 16 + q * 4 + i) * DIM + w * 16 + m;
                xjn[oi] = (unsigned short)f2bf(acc[i]);
            }
        }
    }
}

// fp32 node GEMM kept for lin1 (COLS=64)
template<int COLS, int ACT, int RESID>
__global__ __launch_bounds__(512)
void k_node_gemm(const float* __restrict__ in, const float* __restrict__ W,
                 const float* __restrict__ bias, const float* __restrict__ resid,
                 float* __restrict__ out)
{
    __shared__ float Ws[DIM][COLS];
    __shared__ float rs[EW][EB][DIM];
    int tid = threadIdx.x;
    for (int i = tid; i < DIM * COLS; i += 512) (&Ws[0][0])[i] = W[i];
    __syncthreads();

    int lane = tid & 63;
    int w = tid >> 6;
    int gw = blockIdx.x * EW + w;
    int nw = gridDim.x * EW;
    int ngroups = N_ATOMS / EB;
    constexpr int CPL = COLS / 64;

    float bb[CPL];
    #pragma unroll
    for (int c = 0; c < CPL; ++c) bb[c] = bias ? bias[lane + 64 * c] : 0.0f;

    for (int grp = gw; grp < ngroups; grp += nw) {
        int r0 = grp * EB;
        #pragma unroll
        for (int r = 0; r < EB; ++r) {
            rs[w][r][lane]      = in[(size_t)(r0 + r) * DIM + lane];
            rs[w][r][lane + 64] = in[(size_t)(r0 + r) * DIM + lane + 64];
        }
        float acc[EB][CPL];
        #pragma unroll
        for (int r = 0; r < EB; ++r)
            #pragma unroll
            for (int c = 0; c < CPL; ++c) acc[r][c] = bb[c];
        #pragma unroll 2
        for (int kb = 0; kb < DIM / 4; ++kb) {
            float4 rv[EB];
            #pragma unroll
            for (int r = 0; r < EB; ++r)
                rv[r] = *(const float4*)&rs[w][r][4 * kb];
            #pragma unroll
            for (int j = 0; j < 4; ++j) {
                float wv[CPL];
                #pragma unroll
                for (int c = 0; c < CPL; ++c) wv[c] = Ws[4 * kb + j][lane + 64 * c];
                #pragma unroll
                for (int r = 0; r < EB; ++r) {
                    float rj = ((const float*)&rv[r])[j];
                    #pragma unroll
                    for (int c = 0; c < CPL; ++c)
                        acc[r][c] = fmaf(rj, wv[c], acc[r][c]);
                }
            }
        }
        #pragma unroll
        for (int r = 0; r < EB; ++r) {
            #pragma unroll
            for (int c = 0; c < CPL; ++c) {
                float v = acc[r][c];
                if (ACT) v = ssp_f(v);
                size_t oi = (size_t)(r0 + r) * COLS + lane + 64 * c;
                if (RESID) v += resid[oi];
                out[oi] = v;
            }
        }
    }
}

// per-atom: dot(r1[n], lin2W) + lin2b -> per-block LDS mol reduce -> 32 atomics
__global__ __launch_bounds__(256)
void k_final(const float* __restrict__ r1, const float* __restrict__ l2W,
             const float* __restrict__ l2b, const int* __restrict__ batch,
             float* __restrict__ out)
{
    __shared__ float mols[NMOLS];
    int tid = threadIdx.x;
    if (tid < NMOLS) mols[tid] = 0.0f;
    __syncthreads();

    int n = blockIdx.x * 256 + tid;
    const float4* row = (const float4*)(r1 + (size_t)n * 64);
    const float4* wv  = (const float4*)l2W;
    float s = 0.0f;
    #pragma unroll
    for (int k = 0; k < 16; ++k) {
        float4 a = row[k], b = wv[k];
        s += a.x * b.x + a.y * b.y + a.z * b.z + a.w * b.w;
    }
    s += l2b[0];
    atomicAdd(&mols[batch[n]], s);   // LDS atomic (block-local)
    __syncthreads();
    if (tid < NMOLS) atomicAdd(&out[tid], mols[tid]);
}

extern "C" void kernel_launch(void* const* d_in, const int* in_sizes, int n_in,
                              void* d_out, int out_size, void* d_ws, size_t ws_size,
                              hipStream_t stream) {
    const float* z     = (const float*)d_in[0];
    const float* pos   = (const float*)d_in[1];
    const int*   batch = (const int*)d_in[2];
    const int*   esrc  = (const int*)d_in[3];
    const int*   edst  = (const int*)d_in[4];
    const float* embW  = (const float*)d_in[5];
    const float* embB  = (const float*)d_in[6];
    const float* mlpW1 = (const float*)d_in[7];
    const float* mlpB1 = (const float*)d_in[8];
    const float* mlpW2 = (const float*)d_in[9];
    const float* mlpB2 = (const float*)d_in[10];
    const float* cf1W  = (const float*)d_in[11];
    const float* cf2W  = (const float*)d_in[12];
    const float* cf2B  = (const float*)d_in[13];
    const float* intW  = (const float*)d_in[14];
    const float* intB  = (const float*)d_in[15];
    const float* l1W   = (const float*)d_in[16];
    const float* l1B   = (const float*)d_in[17];
    const float* l2W   = (const float*)d_in[18];
    const float* l2B   = (const float*)d_in[19];
    float* out = (float*)d_out;

    char* ws = (char*)d_ws;
    float* h     = (float*)(ws);                        // 8 MB
    float* dist  = (float*)(ws + (size_t)( 8 << 20));   // 1 MB
    float* Cv    = (float*)(ws + (size_t)( 9 << 20));   // 1 MB
    unsigned short* xj = (unsigned short*)(ws + (size_t)(10 << 20)); // 4 MB bf16
    float* agg   = (float*)(ws + (size_t)(18 << 20));   // 8 MB (reused as r1)
    short* rbfF  = (short*)(ws + (size_t)(26 << 20));   // 32 MB bf16 A-fragments
    int*   deg   = (int*)  (ws + (size_t)(58 << 20));   // 64 KB
    int*   cur   = (int*)  (ws + (size_t)(59 << 20));   // 64 KB
    int*   edge_of = (int*)(ws + (size_t)(60 << 20));   // 1 MB
    float* distS = (float*)(ws + (size_t)(61 << 20));   // 1 MB
    float* CenvS = (float*)(ws + (size_t)(62 << 20));   // 1 MB
    int*   srcS  = (int*)  (ws + (size_t)(63 << 20));   // 1 MB
    int*   dstS  = (int*)  (ws + (size_t)(64 << 20));   // 1 MB
    float* r1    = agg;

    k_embed_geom<<<dim3(N_ATOMS * DIM / 512), dim3(512), 0, stream>>>(
        z, embW, embB, h, pos, esrc, edst, dist, Cv);

    // CSR build (dst-sorted slot permutation)
    hipMemsetAsync(deg, 0, N_ATOMS * sizeof(int), stream);
    k_deg<<<dim3(N_EDGES / 512), dim3(512), 0, stream>>>(edst, deg);
    k_scan<<<dim3(1), dim3(1024), 0, stream>>>(deg, cur);
    k_fill<<<dim3(N_EDGES / 512), dim3(512), 0, stream>>>(edst, cur, edge_of);
    k_perm<<<dim3(N_EDGES / 512), dim3(512), 0, stream>>>(edge_of, dist, Cv, esrc, edst,
                                                          distS, CenvS, srcS, dstS);
    k_rbf<<<dim3(N_EDGES / 16 / 8), dim3(512), 0, stream>>>(distS, rbfF);

    // layer 0 cf1: h @ cf1W[0] -> xj (bf16); also zeroes agg
    k_node_mfma<0, 0, 1><<<dim3(N_ATOMS / 32), dim3(512), 0, stream>>>(
        h, cf1W, nullptr, nullptr, (void*)xj, agg);

    for (int l = 0; l < NL; ++l) {
        k_edge_csr<<<dim3(1024), dim3(512), 0, stream>>>(
            rbfF, CenvS, srcS, dstS,
            mlpW1 + (size_t)l * NG * NF, mlpB1 + (size_t)l * NF,
            mlpW2 + (size_t)l * NF * NF, mlpB2 + (size_t)l * NF,
            xj, agg);
        if (l < NL - 1) {
            // fused cf2+int_lin+next cf1: h updated, xj for layer l+1, agg zeroed
            k_node_fused<1><<<dim3(N_ATOMS / 32), dim3(512), 0, stream>>>(
                agg, cf2W + (size_t)l * NF * DIM, cf2B + (size_t)l * DIM,
                intW + (size_t)l * DIM * DIM, intB + (size_t)l * DIM, h,
                cf1W + (size_t)(l + 1) * DIM * NF, xj, agg);
        } else {
            k_node_fused<0><<<dim3(N_ATOMS / 32), dim3(512), 0, stream>>>(
                agg, cf2W + (size_t)l * NF * DIM, cf2B + (size_t)l * DIM,
                intW + (size_t)l * DIM * DIM, intB + (size_t)l * DIM, h,
                nullptr, nullptr, nullptr);
        }
    }

    k_node_gemm<64, 1, 0><<<dim3(256), dim3(512), 0, stream>>>(h, l1W, l1B, nullptr, r1);
    hipMemsetAsync(out, 0, NMOLS * sizeof(float), stream);
    k_final<<<dim3(N_ATOMS / 256), dim3(256), 0, stream>>>(r1, l2W, l2B, batch, out);
}

// Round 15
// 447.118 us; speedup vs baseline: 1.9525x; 1.0368x over previous
//
#include <hip/hip_runtime.h>
#include <hip/hip_bf16.h>
#include <math.h>

#define N_ATOMS 16384
#define N_EDGES 262144
#define DIM 128
#define NF 128
#define NG 50
#define NL 4
#define NMOLS 32
#define EW 8

typedef short bf16x8 __attribute__((ext_vector_type(8)));
typedef float f32x4 __attribute__((ext_vector_type(4)));

__device__ __forceinline__ float ssp_f(float x) {
    // softplus(x) - log(2) = max(x,0) + log(1 + exp(-|x|)) - log(2)
    float e = __expf(-fabsf(x));
    return fmaxf(x, 0.0f) + __logf(1.0f + e) - 0.6931471805599453f;
}

__device__ __forceinline__ short f2bf(float x) {
    __hip_bfloat16 b = __float2bfloat16(x);  // RNE
    return *reinterpret_cast<short*>(&b);
}

__device__ __forceinline__ float bf2f(unsigned short u) {
    unsigned int v = ((unsigned int)u) << 16;
    return __builtin_bit_cast(float, v);
}

// Merged: h = z*emb_W + emb_b (all blocks); dist/Cenv/deg (first 512 blocks)
__global__ __launch_bounds__(512)
void k_embed_geom(const float* __restrict__ z, const float* __restrict__ Wv,
                  const float* __restrict__ bv, float* __restrict__ h,
                  const float* __restrict__ pos, const int* __restrict__ src,
                  const int* __restrict__ dst, float* __restrict__ dist,
                  float* __restrict__ Cenv, int* __restrict__ deg) {
    int idx = blockIdx.x * 512 + threadIdx.x;
    int n = idx >> 7, d = idx & 127;
    h[idx] = z[n] * Wv[d] + bv[d];
    if (blockIdx.x < N_EDGES / 512) {
        int e = blockIdx.x * 512 + threadIdx.x;
        int s = src[e], t = dst[e];
        float dx = pos[3*s]   - pos[3*t];
        float dy = pos[3*s+1] - pos[3*t+1];
        float dz = pos[3*s+2] - pos[3*t+2];
        float dd = sqrtf(dx*dx + dy*dy + dz*dz + 1e-12f);
        dist[e] = dd;
        Cenv[e] = 0.5f * (cosf(dd * (float)(M_PI / 5.0)) + 1.0f);
        atomicAdd(&deg[t], 1);
    }
}

__global__ __launch_bounds__(1024)
void k_scan(const int* __restrict__ deg, int* __restrict__ cur) {
    __shared__ int tot[1024];
    int t = threadIdx.x;
    int v[16];
    int s = 0;
    #pragma unroll
    for (int j = 0; j < 16; ++j) { int x = deg[t * 16 + j]; v[j] = s; s += x; }
    tot[t] = s;
    __syncthreads();
    for (int off = 1; off < 1024; off <<= 1) {
        int add = (t >= off) ? tot[t - off] : 0;
        __syncthreads();
        tot[t] += add;
        __syncthreads();
    }
    int base = (t == 0) ? 0 : tot[t - 1];
    #pragma unroll
    for (int j = 0; j < 16; ++j) cur[t * 16 + j] = base + v[j];
}

__global__ void k_fill(const int* __restrict__ dst, int* __restrict__ cur,
                       int* __restrict__ edge_of) {
    int e = blockIdx.x * blockDim.x + threadIdx.x;
    if (e < N_EDGES) {
        int p = atomicAdd(&cur[dst[e]], 1);
        edge_of[p] = e;
    }
}

// Merged permute + rbf: thread p emits slot-p metadata and its 64 rbf bf16
// values directly in MFMA A-fragment layout (no distS intermediate).
__global__ __launch_bounds__(512)
void k_perm_rbf(const int* __restrict__ edge_of, const float* __restrict__ dist,
                const float* __restrict__ Cenv, const int* __restrict__ src,
                const int* __restrict__ dst, float* __restrict__ CenvS,
                int* __restrict__ srcS, int* __restrict__ dstS,
                short* __restrict__ rbfF) {
    int p = blockIdx.x * blockDim.x + threadIdx.x;
    if (p >= N_EDGES) return;
    int e = edge_of[p];
    float d = dist[e];
    CenvS[p] = Cenv[e];
    srcS[p]  = src[e];
    dstS[p]  = dst[e];
    int t = p >> 4, m = p & 15;
    #pragma unroll
    for (int kc = 0; kc < 2; ++kc) {
        #pragma unroll
        for (int q = 0; q < 4; ++q) {
            bf16x8 v;
            #pragma unroll
            for (int j = 0; j < 8; ++j) {
                float mu = (float)(kc * 32 + q * 8 + j) * (5.0f / 49.0f);
                float tt = d - mu;
                v[j] = f2bf(__expf(-4.0f * tt * tt));   // k>=50 rows hit zero W1R
            }
            *(bf16x8*)&rbfF[(size_t)((t * 2 + kc) * 64 + q * 16 + m) * 8] = v;
        }
    }
}

// MFMA edge pipeline over dst-sorted slots (r12 structure, unchanged).
__global__ __launch_bounds__(512, 4)
void k_edge_csr(const short* __restrict__ rbfF, const float* __restrict__ CenvS,
                const int* __restrict__ srcS, const int* __restrict__ dstS,
                const float* __restrict__ W1, const float* __restrict__ b1,
                const float* __restrict__ W2, const float* __restrict__ b2,
                const unsigned short* __restrict__ xjb, float* __restrict__ agg)
{
    __shared__ short H1s[64 * 128];              // 16 KB
    __shared__ unsigned short msgt[64][136];     // 17 KB bf16 message tile (+16B pad)
    __shared__ int dsts[64];
    __shared__ unsigned long long maskS;
    const int tid  = threadIdx.x;
    const int lane = tid & 63;
    const int w    = tid >> 6;     // wave id = filter block
    const int q    = lane >> 4;
    const int m    = lane & 15;

    bf16x8 W1R[2], W2R[4];
    #pragma unroll
    for (int kc = 0; kc < 2; ++kc) {
        bf16x8 f;
        #pragma unroll
        for (int j = 0; j < 8; ++j) {
            int k = kc * 32 + q * 8 + j;
            float v = (k < NG) ? W1[k * NF + w * 16 + m] : 0.0f;  // pad G 50->64
            f[j] = f2bf(v);
        }
        W1R[kc] = f;
    }
    #pragma unroll
    for (int kc = 0; kc < 4; ++kc) {
        bf16x8 f;
        #pragma unroll
        for (int j = 0; j < 8; ++j) {
            int k = kc * 32 + q * 8 + j;
            f[j] = f2bf(W2[k * NF + w * 16 + m]);
        }
        W2R[kc] = f;
    }
    const float b1v = b1[w * 16 + m];
    const float b2v = b2[w * 16 + m];

    const int nrounds = N_EDGES / 64;
    for (int r = blockIdx.x; r < nrounds; r += gridDim.x) {
        const int p0 = r * 64;
        short* H = H1s;

        // ---- matvec1: A from precomputed rbfF + ssp + swizzled H1 store ----
        #pragma unroll
        for (int a = 0; a < 4; ++a) {
            int tile = r * 4 + a;
            f32x4 acc = {b1v, b1v, b1v, b1v};
            #pragma unroll
            for (int kc = 0; kc < 2; ++kc) {
                bf16x8 A = *(const bf16x8*)&rbfF[(size_t)((tile * 2 + kc) * 64 + lane) * 8];
                acc = __builtin_amdgcn_mfma_f32_16x16x32_bf16(A, W1R[kc], acc, 0, 0, 0);
            }
            #pragma unroll
            for (int i = 0; i < 4; ++i) {
                int e = a * 16 + q * 4 + i;
                int f = w * 16 + m;
                int byte = (e * 256 + f * 2) ^ ((e & 7) << 4);
                *(short*)((char*)H + byte) = f2bf(ssp_f(acc[i]));
            }
        }
        __syncthreads();   // A: H1 write -> read

        // ---- issue xj gathers now; they fly during matvec2 (T14 issue-early) ----
        unsigned short xu[4][4];
        #pragma unroll
        for (int a = 0; a < 4; ++a) {
            int4 s4 = *(const int4*)&srcS[p0 + a * 16 + q * 4];
            #pragma unroll
            for (int i = 0; i < 4; ++i)
                xu[a][i] = xjb[(size_t)((const int*)&s4)[i] * NF + w * 16 + m];
        }

        // ---- matvec2: Wf = H1 @ W2 + b2 ----
        f32x4 acc2[4];
        #pragma unroll
        for (int a = 0; a < 4; ++a) {
            f32x4 acc = {b2v, b2v, b2v, b2v};
            #pragma unroll
            for (int kc = 0; kc < 4; ++kc) {
                int e = a * 16 + m;
                int byte = (e * 256 + (kc * 32 + q * 8) * 2) ^ ((e & 7) << 4);
                bf16x8 A = *(const bf16x8*)((const char*)H + byte);  // ds_read_b128
                acc = __builtin_amdgcn_mfma_f32_16x16x32_bf16(A, W2R[kc], acc, 0, 0, 0);
            }
            acc2[a] = acc;
        }

        // ---- messages -> LDS tile (bf16): v = Wf * C * xv ----
        #pragma unroll
        for (int a = 0; a < 4; ++a) {
            float4 cc4 = *(const float4*)&CenvS[p0 + a * 16 + q * 4];
            #pragma unroll
            for (int i = 0; i < 4; ++i) {
                float v = acc2[a][i] * ((const float*)&cc4)[i];
                msgt[a * 16 + q * 4 + i][w * 16 + m] =
                    (unsigned short)f2bf(v * bf2f(xu[a][i]));
            }
        }
        if (w == 0) {
            int d = dstS[p0 + lane];
            int prev = __shfl_up(d, 1);
            bool head = (lane == 0) || (d != prev);
            unsigned long long mk = __ballot(head);
            dsts[lane] = d;
            if (lane == 0) maskS = mk;
        }
        __syncthreads();   // B: msgt/dsts write -> reduce

        // ---- run-segmented reduce: 128 threads x 4 run-groups, ILP-4 sums ----
        {
            int f = tid & 127;
            int g = tid >> 7;
            unsigned long long mm = maskS;
            int k = 0;
            while (mm) {
                int start = __ffsll(mm) - 1;
                mm &= mm - 1;
                int end = mm ? (__ffsll(mm) - 1) : 64;
                if ((k & 3) == g) {
                    float s0 = 0.0f, s1 = 0.0f, s2 = 0.0f, s3 = 0.0f;
                    int p = start;
                    for (; p + 4 <= end; p += 4) {   // 4 independent LDS chains
                        s0 += bf2f(msgt[p    ][f]);
                        s1 += bf2f(msgt[p + 1][f]);
                        s2 += bf2f(msgt[p + 2][f]);
                        s3 += bf2f(msgt[p + 3][f]);
                    }
                    for (; p < end; ++p) s0 += bf2f(msgt[p][f]);
                    float s = (s0 + s1) + (s2 + s3);
                    float* addr = &agg[(size_t)dsts[start] * NF + f];
                    if (start == 0 || end == 64) atomicAdd(addr, s);  // run may span rounds
                    else *addr = s;                                    // run exclusive here
                }
                ++k;
            }
        }
    }
}

// MFMA node GEMM (single stage): out = post(in @ W + bias); 32-row tiles.
// aggz != nullptr: also zero this block's rows of aggz.
template<int ACT, int RESID, int OUTBF>
__global__ __launch_bounds__(512, 2)
void k_node_mfma(const float* __restrict__ in, const float* __restrict__ W,
                 const float* __restrict__ bias, const float* __restrict__ resid,
                 void* __restrict__ outv, float* __restrict__ aggz)
{
    __shared__ short T[32 * 128];   // 8 KB swizzled bf16 tile
    const int tid  = threadIdx.x;
    const int lane = tid & 63;
    const int w    = tid >> 6;
    const int q    = lane >> 4;
    const int m    = lane & 15;

    bf16x8 WR[4];
    #pragma unroll
    for (int kc = 0; kc < 4; ++kc) {
        bf16x8 f;
        #pragma unroll
        for (int j = 0; j < 8; ++j)
            f[j] = f2bf(W[(kc * 32 + q * 8 + j) * DIM + w * 16 + m]);
        WR[kc] = f;
    }
    const float bv = bias ? bias[w * 16 + m] : 0.0f;

    const int r0 = blockIdx.x * 32;

    {
        int row = tid >> 4;
        int k0  = (tid & 15) * 8;
        const float* src = in + (size_t)(r0 + row) * DIM + k0;
        float4 v0 = *(const float4*)(src);
        float4 v1 = *(const float4*)(src + 4);
        bf16x8 lo;
        #pragma unroll
        for (int j = 0; j < 4; ++j) {
            lo[j]     = f2bf(((const float*)&v0)[j]);
            lo[j + 4] = f2bf(((const float*)&v1)[j]);
        }
        int b0 = (row * 256 + k0 * 2) ^ ((row & 7) << 4);
        *(bf16x8*)((char*)T + b0) = lo;
        if (aggz) {
            float4 zz = {0.0f, 0.0f, 0.0f, 0.0f};
            float* dz = aggz + (size_t)(r0 + row) * DIM + k0;
            *(float4*)dz = zz;
            *(float4*)(dz + 4) = zz;
        }
    }
    __syncthreads();

    #pragma unroll
    for (int a = 0; a < 2; ++a) {
        f32x4 acc = {bv, bv, bv, bv};
        int row = a * 16 + m;
        #pragma unroll
        for (int kc = 0; kc < 4; ++kc) {
            int byte = (row * 256 + (kc * 32 + q * 8) * 2) ^ ((row & 7) << 4);
            bf16x8 A = *(const bf16x8*)((const char*)T + byte);
            acc = __builtin_amdgcn_mfma_f32_16x16x32_bf16(A, WR[kc], acc, 0, 0, 0);
        }
        #pragma unroll
        for (int i = 0; i < 4; ++i) {
            float v = acc[i];
            if (ACT) v = ssp_f(v);
            size_t oi = (size_t)(r0 + a * 16 + q * 4 + i) * DIM + w * 16 + m;
            if (RESID) v += resid[oi];
            if (OUTBF) ((unsigned short*)outv)[oi] = (unsigned short)f2bf(v);
            else       ((float*)outv)[oi] = v;
        }
    }
}

// Fused cf2 + int_lin (+ EMIT: next cf1 | FINAL: lin1+lin2+mol reduce):
//   hn = h + ssp(agg @ W2 + b2) @ Wi + bi ; h = hn
//   EMIT:  xjn = hn @ W1n (bf16), zero agg rows
//   FINAL: r1 = ssp(hn @ l1W + l1B); s = r1 . l2W + l2b; out[batch] += s
template<int EMIT, int FINAL>
__global__ __launch_bounds__(512, 2)
void k_node_fused(const float* __restrict__ agg, const float* __restrict__ W2,
                  const float* __restrict__ b2, const float* __restrict__ Wi,
                  const float* __restrict__ bi, float* __restrict__ h,
                  const float* __restrict__ W1n, unsigned short* __restrict__ xjn,
                  float* __restrict__ aggz,
                  const float* __restrict__ l1W, const float* __restrict__ l1B,
                  const float* __restrict__ l2W, const float* __restrict__ l2b,
                  const int* __restrict__ batch, float* __restrict__ out)
{
    __shared__ short T[32 * 128];   // 8 KB: input tile, later hn^T tile
    __shared__ short X[32 * 128];   // 8 KB: intermediate tile
    __shared__ float part[32][4];
    __shared__ float molsS[NMOLS];
    const int tid  = threadIdx.x;
    const int lane = tid & 63;
    const int w    = tid >> 6;
    const int q    = lane >> 4;
    const int m    = lane & 15;

    if (FINAL && tid < NMOLS) molsS[tid] = 0.0f;

    bf16x8 W2R[4], WiR[4], W1nR[4], L1R[4];
    #pragma unroll
    for (int kc = 0; kc < 4; ++kc) {
        bf16x8 f2v, fiv;
        #pragma unroll
        for (int j = 0; j < 8; ++j) {
            int k = kc * 32 + q * 8 + j;
            f2v[j] = f2bf(W2[k * DIM + w * 16 + m]);
            fiv[j] = f2bf(Wi[k * DIM + w * 16 + m]);
        }
        W2R[kc] = f2v;
        WiR[kc] = fiv;
    }
    if constexpr (EMIT) {
        #pragma unroll
        for (int kc = 0; kc < 4; ++kc) {
            bf16x8 f;
            #pragma unroll
            for (int j = 0; j < 8; ++j)
                f[j] = f2bf(W1n[(kc * 32 + q * 8 + j) * DIM + w * 16 + m]);
            W1nR[kc] = f;
        }
    }
    if constexpr (FINAL) {
        if (w < 4) {
            #pragma unroll
            for (int kc = 0; kc < 4; ++kc) {
                bf16x8 f;
                #pragma unroll
                for (int j = 0; j < 8; ++j)
                    f[j] = f2bf(l1W[(kc * 32 + q * 8 + j) * 64 + w * 16 + m]);
                L1R[kc] = f;
            }
        }
    }
    const float b2v = b2[w * 16 + m];
    const float biv = bi[w * 16 + m];

    const int r0 = blockIdx.x * 32;
    const int srow = tid >> 4;
    const int sk0  = (tid & 15) * 8;

    // ---- stage agg tile -> T ----
    {
        const float* src = agg + (size_t)(r0 + srow) * DIM + sk0;
        float4 v0 = *(const float4*)(src);
        float4 v1 = *(const float4*)(src + 4);
        bf16x8 lo;
        #pragma unroll
        for (int j = 0; j < 4; ++j) {
            lo[j]     = f2bf(((const float*)&v0)[j]);
            lo[j + 4] = f2bf(((const float*)&v1)[j]);
        }
        int b0 = (srow * 256 + sk0 * 2) ^ ((srow & 7) << 4);
        *(bf16x8*)((char*)T + b0) = lo;
    }
    __syncthreads();   // bar1: T ready

    // ---- stage 1: X = ssp(T @ W2 + b2) (transposed swizzled store) ----
    #pragma unroll
    for (int a = 0; a < 2; ++a) {
        f32x4 acc = {b2v, b2v, b2v, b2v};
        int row = a * 16 + m;
        #pragma unroll
        for (int kc = 0; kc < 4; ++kc) {
            int byte = (row * 256 + (kc * 32 + q * 8) * 2) ^ ((row & 7) << 4);
            bf16x8 A = *(const bf16x8*)((const char*)T + byte);
            acc = __builtin_amdgcn_mfma_f32_16x16x32_bf16(A, W2R[kc], acc, 0, 0, 0);
        }
        #pragma unroll
        for (int i = 0; i < 4; ++i) {
            int orow = a * 16 + q * 4 + i;
            int ocol = w * 16 + m;
            int byte = (orow * 256 + ocol * 2) ^ ((orow & 7) << 4);
            *(short*)((char*)X + byte) = f2bf(ssp_f(acc[i]));
        }
    }
    __syncthreads();   // bar2: X ready; all T reads done (T now reusable)

    // ---- stage 2: hn = h + X @ Wi + bi; write h; stash hn^T into T ----
    #pragma unroll
    for (int a = 0; a < 2; ++a) {
        f32x4 acc = {biv, biv, biv, biv};
        int row = a * 16 + m;
        #pragma unroll
        for (int kc = 0; kc < 4; ++kc) {
            int byte = (row * 256 + (kc * 32 + q * 8) * 2) ^ ((row & 7) << 4);
            bf16x8 A = *(const bf16x8*)((const char*)X + byte);
            acc = __builtin_amdgcn_mfma_f32_16x16x32_bf16(A, WiR[kc], acc, 0, 0, 0);
        }
        #pragma unroll
        for (int i = 0; i < 4; ++i) {
            size_t oi = (size_t)(r0 + a * 16 + q * 4 + i) * DIM + w * 16 + m;
            float v = h[oi] + acc[i];
            h[oi] = v;
            if constexpr (EMIT || FINAL) {
                int orow = a * 16 + q * 4 + i;
                int ocol = w * 16 + m;
                int byte = (orow * 256 + ocol * 2) ^ ((orow & 7) << 4);
                *(short*)((char*)T + byte) = f2bf(v);
            }
        }
    }

    if constexpr (EMIT) {
        // zero this block's agg rows for the next edge pass (reads done pre-bar1)
        float4 zz = {0.0f, 0.0f, 0.0f, 0.0f};
        float* dz = aggz + (size_t)(r0 + srow) * DIM + sk0;
        *(float4*)dz = zz;
        *(float4*)(dz + 4) = zz;
    }
    if constexpr (EMIT || FINAL) __syncthreads();   // bar3: hn^T tile ready

    if constexpr (EMIT) {
        // ---- stage 3: xjn = hn @ W1n (no bias) ----
        #pragma unroll
        for (int a = 0; a < 2; ++a) {
            f32x4 acc = {0.0f, 0.0f, 0.0f, 0.0f};
            int row = a * 16 + m;
            #pragma unroll
            for (int kc = 0; kc < 4; ++kc) {
                int byte = (row * 256 + (kc * 32 + q * 8) * 2) ^ ((row & 7) << 4);
                bf16x8 A = *(const bf16x8*)((const char*)T + byte);
                acc = __builtin_amdgcn_mfma_f32_16x16x32_bf16(A, W1nR[kc], acc, 0, 0, 0);
            }
            #pragma unroll
            for (int i = 0; i < 4; ++i) {
                size_t oi = (size_t)(r0 + a * 16 + q * 4 + i) * DIM + w * 16 + m;
                xjn[oi] = (unsigned short)f2bf(acc[i]);
            }
        }
    }

    if constexpr (FINAL) {
        // ---- readout: r1 = ssp(hn @ l1W + l1B); s_row = r1 . l2W ----
        if (w < 4) {
            const float l1bv = l1B[w * 16 + m];
            const float l2wv = l2W[w * 16 + m];
            #pragma unroll
            for (int a = 0; a < 2; ++a) {
                f32x4 acc = {l1bv, l1bv, l1bv, l1bv};
                int row = a * 16 + m;
                #pragma unroll
                for (int kc = 0; kc < 4; ++kc) {
                    int byte = (row * 256 + (kc * 32 + q * 8) * 2) ^ ((row & 7) << 4);
                    bf16x8 A = *(const bf16x8*)((const char*)T + byte);
                    acc = __builtin_amdgcn_mfma_f32_16x16x32_bf16(A, L1R[kc], acc, 0, 0, 0);
                }
                #pragma unroll
                for (int i = 0; i < 4; ++i) {
                    float v = ssp_f(acc[i]) * l2wv;
                    // reduce over the 16-lane m-group (lane = q*16+m)
                    #pragma unroll
                    for (int off = 1; off < 16; off <<= 1) v += __shfl_xor(v, off);
                    if (m == 0) part[a * 16 + q * 4 + i][w] = v;
                }
            }
        }
        __syncthreads();   // bar4: part ready
        if (tid < 32) {
            float s = part[tid][0] + part[tid][1] + part[tid][2] + part[tid][3] + l2b[0];
            atomicAdd(&molsS[batch[r0 + tid]], s);   // LDS atomic
        }
        __syncthreads();   // bar5
        if (tid < NMOLS) {
            float v = molsS[tid];
            if (v != 0.0f) atomicAdd(&out[tid], v);  // ~1-2 nonzero mols/block
        }
    }
}

extern "C" void kernel_launch(void* const* d_in, const int* in_sizes, int n_in,
                              void* d_out, int out_size, void* d_ws, size_t ws_size,
                              hipStream_t stream) {
    const float* z     = (const float*)d_in[0];
    const float* pos   = (const float*)d_in[1];
    const int*   batch = (const int*)d_in[2];
    const int*   esrc  = (const int*)d_in[3];
    const int*   edst  = (const int*)d_in[4];
    const float* embW  = (const float*)d_in[5];
    const float* embB  = (const float*)d_in[6];
    const float* mlpW1 = (const float*)d_in[7];
    const float* mlpB1 = (const float*)d_in[8];
    const float* mlpW2 = (const float*)d_in[9];
    const float* mlpB2 = (const float*)d_in[10];
    const float* cf1W  = (const float*)d_in[11];
    const float* cf2W  = (const float*)d_in[12];
    const float* cf2B  = (const float*)d_in[13];
    const float* intW  = (const float*)d_in[14];
    const float* intB  = (const float*)d_in[15];
    const float* l1W   = (const float*)d_in[16];
    const float* l1B   = (const float*)d_in[17];
    const float* l2W   = (const float*)d_in[18];
    const float* l2B   = (const float*)d_in[19];
    float* out = (float*)d_out;

    char* ws = (char*)d_ws;
    float* h     = (float*)(ws);                        // 8 MB
    float* dist  = (float*)(ws + (size_t)( 8 << 20));   // 1 MB
    float* Cv    = (float*)(ws + (size_t)( 9 << 20));   // 1 MB
    unsigned short* xj = (unsigned short*)(ws + (size_t)(10 << 20)); // 4 MB bf16
    float* agg   = (float*)(ws + (size_t)(18 << 20));   // 8 MB
    short* rbfF  = (short*)(ws + (size_t)(26 << 20));   // 32 MB bf16 A-fragments
    int*   deg   = (int*)  (ws + (size_t)(58 << 20));   // 64 KB
    int*   cur   = (int*)  (ws + (size_t)(59 << 20));   // 64 KB
    int*   edge_of = (int*)(ws + (size_t)(60 << 20));   // 1 MB
    float* CenvS = (float*)(ws + (size_t)(62 << 20));   // 1 MB
    int*   srcS  = (int*)  (ws + (size_t)(63 << 20));   // 1 MB
    int*   dstS  = (int*)  (ws + (size_t)(64 << 20));   // 1 MB

    hipMemsetAsync(deg, 0, N_ATOMS * sizeof(int), stream);
    hipMemsetAsync(out, 0, NMOLS * sizeof(float), stream);

    k_embed_geom<<<dim3(N_ATOMS * DIM / 512), dim3(512), 0, stream>>>(
        z, embW, embB, h, pos, esrc, edst, dist, Cv, deg);
    k_scan<<<dim3(1), dim3(1024), 0, stream>>>(deg, cur);
    k_fill<<<dim3(N_EDGES / 512), dim3(512), 0, stream>>>(edst, cur, edge_of);
    k_perm_rbf<<<dim3(N_EDGES / 512), dim3(512), 0, stream>>>(
        edge_of, dist, Cv, esrc, edst, CenvS, srcS, dstS, rbfF);

    // layer 0 cf1: h @ cf1W[0] -> xj (bf16); also zeroes agg
    k_node_mfma<0, 0, 1><<<dim3(N_ATOMS / 32), dim3(512), 0, stream>>>(
        h, cf1W, nullptr, nullptr, (void*)xj, agg);

    for (int l = 0; l < NL; ++l) {
        k_edge_csr<<<dim3(1024), dim3(512), 0, stream>>>(
            rbfF, CenvS, srcS, dstS,
            mlpW1 + (size_t)l * NG * NF, mlpB1 + (size_t)l * NF,
            mlpW2 + (size_t)l * NF * NF, mlpB2 + (size_t)l * NF,
            xj, agg);
        if (l < NL - 1) {
            k_node_fused<1, 0><<<dim3(N_ATOMS / 32), dim3(512), 0, stream>>>(
                agg, cf2W + (size_t)l * NF * DIM, cf2B + (size_t)l * DIM,
                intW + (size_t)l * DIM * DIM, intB + (size_t)l * DIM, h,
                cf1W + (size_t)(l + 1) * DIM * NF, xj, agg,
                nullptr, nullptr, nullptr, nullptr, nullptr, nullptr);
        } else {
            k_node_fused<0, 1><<<dim3(N_ATOMS / 32), dim3(512), 0, stream>>>(
                agg, cf2W + (size_t)l * NF * DIM, cf2B + (size_t)l * DIM,
                intW + (size_t)l * DIM * DIM, intB + (size_t)l * DIM, h,
                nullptr, nullptr, nullptr,
                l1W, l1B, l2W, l2B, batch, out);
        }
    }
}